// Round 4
// baseline (4501.880 us; speedup 1.0000x reference)
//
#include <hip/hip_runtime.h>
#include <cstddef>
#include <cstdint>

// ---- model dims ----
#define L_TOK 392
#define BATCH 8
#define DM    768
#define ED    1536
#define NST   16
#define DTR   48
#define ROWS  (BATCH * L_TOK)   // 3136

// Workspace layout (BYTES, all 16B aligned), total = 49,172,480 B (~47 MB):
//  X    fp32 [ROWS*DM]   residual (persistent across layers)
//  XC   bf16 [ROWS*ED]   conv input; reused for im2col patches & y
//  Z    bf16 [ROWS*ED]   gate half of in_proj
//  XIN  bf16 [ROWS*ED]   conv+silu output
//  DEL  bf16 [ROWS*ED]   delta; front 4.8MB doubles as xn buffer
//  DBC  fp32 [ROWS*80]
// (round-1 overran d_ws at 107MB and corrupted pristine inputs; keep <= 47MB)

typedef unsigned short ushortT;
typedef __bf16 bf16x8 __attribute__((ext_vector_type(8)));
typedef unsigned short us8 __attribute__((ext_vector_type(8)));
typedef unsigned short us4 __attribute__((ext_vector_type(4)));
typedef float f32x4 __attribute__((ext_vector_type(4)));

__device__ __forceinline__ float bf2f(ushortT u) {
    union { unsigned int i; float f; } v; v.i = ((unsigned int)u) << 16; return v.f;
}
__device__ __forceinline__ ushortT f2bf(float f) {
    union { float f; unsigned int i; } v; v.f = f;
    unsigned int r = v.i + 0x7FFFu + ((v.i >> 16) & 1u);   // round-nearest-even
    return (ushortT)(r >> 16);
}

enum { EPI_STORE = 0, EPI_BIAS = 1, EPI_BIAS_SOFTPLUS = 2, EPI_ADD = 3 };

// ----------------------------------------------------------------------------
// MFMA GEMM: C[M,N] (epi)= A[M,K](bf16, lda) @ W[N,K](fp32, ldw)^T
// 128x128 tile, BK=32, 256 threads = 4 waves in 2x2, each wave 64x64 via
// 4x4 v_mfma_f32_16x16x32_bf16.  W converted fp32->bf16 during LDS staging.
// ----------------------------------------------------------------------------
template <int EPI, bool C_BF>
__global__ __launch_bounds__(256)
void gemm_mfma(const ushortT* __restrict__ A, int lda,
               const float* __restrict__ W, int ldw,
               const float* __restrict__ bias,
               void* __restrict__ Cv, int ldc,
               int M, int N, int K)
{
    __shared__ ushortT As[128 * 40];
    __shared__ ushortT Ws[128 * 40];

    const int tid  = threadIdx.x;
    const int lane = tid & 63;
    const int wave = tid >> 6;
    const int wm   = wave >> 1;        // 0..1
    const int wn   = wave & 1;         // 0..1
    const int quad = lane >> 4;        // 0..3
    const int l16  = lane & 15;        // 0..15

    const int m0 = blockIdx.y * 128;
    const int n0 = blockIdx.x * 128;

    const int ar   = tid >> 1;         // 0..127  A row
    const int ahalf= tid & 1;          // 16-elem half
    const int wr   = tid >> 3;         // 0..31   W row (x4 iters)
    const int wc   = (tid & 7) * 4;    // float4 col

    f32x4 acc[4][4] = {};

    for (int k0 = 0; k0 < K; k0 += 32) {
        us8 a0 = {0,0,0,0,0,0,0,0}, a1 = {0,0,0,0,0,0,0,0};
        int gm = m0 + ar;
        if (gm < M) {
            const ushortT* src = A + (size_t)gm * lda + k0 + ahalf * 16;
            a0 = *(const us8*)(src);
            a1 = *(const us8*)(src + 8);
        }
        *(us8*)&As[ar * 40 + ahalf * 16]     = a0;
        *(us8*)&As[ar * 40 + ahalf * 16 + 8] = a1;
#pragma unroll
        for (int it = 0; it < 4; ++it) {
            int row = it * 32 + wr;
            float4 f = *(const float4*)(W + (size_t)(n0 + row) * ldw + k0 + wc);
            us4 h; h.x = f2bf(f.x); h.y = f2bf(f.y); h.z = f2bf(f.z); h.w = f2bf(f.w);
            *(us4*)&Ws[row * 40 + wc] = h;
        }
        __syncthreads();

        bf16x8 af[4], bw[4];
#pragma unroll
        for (int t = 0; t < 4; ++t) {
            us8 ta = *(const us8*)&As[(wm * 64 + t * 16 + l16) * 40 + quad * 8];
            af[t] = __builtin_bit_cast(bf16x8, ta);
            us8 tb = *(const us8*)&Ws[(wn * 64 + t * 16 + l16) * 40 + quad * 8];
            bw[t] = __builtin_bit_cast(bf16x8, tb);
        }
#pragma unroll
        for (int i = 0; i < 4; ++i)
#pragma unroll
            for (int j = 0; j < 4; ++j)
                acc[i][j] = __builtin_amdgcn_mfma_f32_16x16x32_bf16(
                    af[i], bw[j], acc[i][j], 0, 0, 0);
        __syncthreads();
    }

#pragma unroll
    for (int i = 0; i < 4; ++i) {
#pragma unroll
        for (int r = 0; r < 4; ++r) {
            int gm = m0 + wm * 64 + i * 16 + quad * 4 + r;
            if (gm >= M) continue;
#pragma unroll
            for (int j = 0; j < 4; ++j) {
                int gn = n0 + wn * 64 + j * 16 + l16;
                float v = acc[i][j][r];
                if (EPI == EPI_BIAS) v += bias[gn];
                size_t off = (size_t)gm * ldc + gn;
                if (C_BF) {
                    ((ushortT*)Cv)[off] = f2bf(v);
                } else {
                    float* p = (float*)Cv + off;
                    *p = (EPI == EPI_ADD) ? v + *p : v;
                }
            }
        }
    }
}

// ----------------------------------------------------------------------------
// VALU tiled GEMM for the small shapes (x_proj N=80, dt_proj K=48).
// ----------------------------------------------------------------------------
template <int EPI, bool A_BF, bool C_BF>
__global__ __launch_bounds__(256)
void gemm_nt(const void* __restrict__ Av, int lda,
             const float* __restrict__ W, int ldw,
             const float* __restrict__ bias,
             void* __restrict__ Cv, int ldc,
             int M, int N, int K)
{
    __shared__ float As[16][68];
    __shared__ float Bs[16][68];
    const int tid = threadIdx.x;
    const int tx  = tid & 15;
    const int ty  = tid >> 4;
    const int bm  = blockIdx.y * 64;
    const int bn  = blockIdx.x * 64;
    const int lr  = tid >> 2;
    const int lk  = (tid & 3) * 4;

    float acc[4][4] = {};

    for (int k0 = 0; k0 < K; k0 += 16) {
        float a0 = 0.f, a1 = 0.f, a2 = 0.f, a3 = 0.f;
        float w0 = 0.f, w1 = 0.f, w2 = 0.f, w3 = 0.f;
        int ga = bm + lr;
        if (ga < M) {
            if (A_BF) {
                const ushortT* A = (const ushortT*)Av;
                ushort4 t = *(const ushort4*)(A + (size_t)ga * lda + k0 + lk);
                a0 = bf2f(t.x); a1 = bf2f(t.y); a2 = bf2f(t.z); a3 = bf2f(t.w);
            } else {
                const float* A = (const float*)Av;
                float4 t = *(const float4*)(A + (size_t)ga * lda + k0 + lk);
                a0 = t.x; a1 = t.y; a2 = t.z; a3 = t.w;
            }
        }
        int gw = bn + lr;
        if (gw < N) {
            float4 t = *(const float4*)(W + (size_t)gw * ldw + k0 + lk);
            w0 = t.x; w1 = t.y; w2 = t.z; w3 = t.w;
        }
        As[lk + 0][lr] = a0; As[lk + 1][lr] = a1;
        As[lk + 2][lr] = a2; As[lk + 3][lr] = a3;
        Bs[lk + 0][lr] = w0; Bs[lk + 1][lr] = w1;
        Bs[lk + 2][lr] = w2; Bs[lk + 3][lr] = w3;
        __syncthreads();
#pragma unroll
        for (int k = 0; k < 16; ++k) {
            float4 a4 = *(const float4*)&As[k][ty * 4];
            float4 b4 = *(const float4*)&Bs[k][tx * 4];
            float a[4] = {a4.x, a4.y, a4.z, a4.w};
            float b[4] = {b4.x, b4.y, b4.z, b4.w};
#pragma unroll
            for (int i = 0; i < 4; ++i)
#pragma unroll
                for (int j = 0; j < 4; ++j)
                    acc[i][j] += a[i] * b[j];
        }
        __syncthreads();
    }

#pragma unroll
    for (int i = 0; i < 4; ++i) {
        int gm = bm + ty * 4 + i;
        if (gm >= M) continue;
#pragma unroll
        for (int j = 0; j < 4; ++j) {
            int gn = bn + tx * 4 + j;
            if (gn >= N) continue;
            float v = acc[i][j];
            if (EPI == EPI_BIAS) v += bias[gn];
            if (EPI == EPI_BIAS_SOFTPLUS) {
                v += bias[gn];
                v = fmaxf(v, 0.f) + log1pf(expf(-fabsf(v)));  // softplus
            }
            size_t off = (size_t)gm * ldc + gn;
            if (C_BF) {
                ((ushortT*)Cv)[off] = f2bf(v);
            } else {
                float* p = (float*)Cv + off;
                *p = (EPI == EPI_ADD) ? v + *p : v;
            }
        }
    }
}

// ----------------------------------------------------------------------------
// RMSNorm: xn[r,:] = x[r,:] * rsqrt(mean(x^2)+1e-5) * w   (768/row, bf16 out)
// ----------------------------------------------------------------------------
__global__ __launch_bounds__(256)
void rmsnorm_kernel(const float* __restrict__ x, const float* __restrict__ w,
                    ushortT* __restrict__ xn)
{
    int r = blockIdx.x;
    const float* xr = x + (size_t)r * DM;
    float v[3];
    float s = 0.f;
#pragma unroll
    for (int i = 0; i < 3; ++i) {
        v[i] = xr[threadIdx.x + i * 256];
        s += v[i] * v[i];
    }
#pragma unroll
    for (int o = 32; o > 0; o >>= 1) s += __shfl_down(s, o, 64);
    __shared__ float wsum[4];
    __shared__ float scale_s;
    int wave = threadIdx.x >> 6;
    if ((threadIdx.x & 63) == 0) wsum[wave] = s;
    __syncthreads();
    if (threadIdx.x == 0) {
        float t = wsum[0] + wsum[1] + wsum[2] + wsum[3];
        scale_s = rsqrtf(t * (1.f / 768.f) + 1e-5f);
    }
    __syncthreads();
    float sc = scale_s;
#pragma unroll
    for (int i = 0; i < 3; ++i) {
        int d = threadIdx.x + i * 256;
        xn[(size_t)r * DM + d] = f2bf(v[i] * sc * w[d]);
    }
}

// ----------------------------------------------------------------------------
// Causal depthwise conv (width 4) + bias + silu.
// ----------------------------------------------------------------------------
__global__ __launch_bounds__(256)
void conv_silu_kernel(const ushortT* __restrict__ xc, const float* __restrict__ cw,
                      const float* __restrict__ cb, ushortT* __restrict__ xin)
{
    int idx = blockIdx.x * 256 + threadIdx.x;
    if (idx >= ROWS * ED) return;
    int e = idx % ED;
    int r = idx / ED;
    int l = r % L_TOK;
    float w0 = cw[e * 4 + 0], w1 = cw[e * 4 + 1];
    float w2 = cw[e * 4 + 2], w3 = cw[e * 4 + 3];
    const ushortT* base = xc + (size_t)r * ED + e;
    float acc = cb[e] + w3 * bf2f(base[0]);
    if (l >= 1) acc += w2 * bf2f(base[-(ptrdiff_t)ED]);
    if (l >= 2) acc += w1 * bf2f(base[-(ptrdiff_t)(2 * ED)]);
    if (l >= 3) acc += w0 * bf2f(base[-(ptrdiff_t)(3 * ED)]);
    xin[(size_t)r * ED + e] = f2bf(acc / (1.f + __expf(-acc)));  // silu
}

// ----------------------------------------------------------------------------
// Selective scan, fused with +D*xin and *silu(z).
// Block = 256 threads = 16 channels x 16 states.
// Depth-8 software pipeline: loads for step l+8 issue at step l, so ~40
// loads/wave stay in flight (was depth-1 -> latency-bound at 457ns/step).
// ----------------------------------------------------------------------------
#define PF 8   // 392 % 8 == 0
__global__ __launch_bounds__(256)
void scan_kernel(const ushortT* __restrict__ delta, const ushortT* __restrict__ xin,
                 const float* __restrict__ dbc, const ushortT* __restrict__ zb,
                 const float* __restrict__ a_log, const float* __restrict__ dvec,
                 ushortT* __restrict__ y)
{
    int tid = threadIdx.x;
    int n  = tid & 15;
    int el = tid >> 4;
    int b  = blockIdx.x / (ED / 16);
    int e  = (blockIdx.x % (ED / 16)) * 16 + el;

    float a   = -expf(a_log[e * NST + n]);   // A = -exp(A_log)
    float dcf = dvec[e];
    float h = 0.f;

    const int rb = b * L_TOK;
    const size_t base = (size_t)rb * ED + e;   // bf16 arrays, stride ED per step

    float dl[PF], xi[PF], Bn[PF], Cn[PF], zz[PF];
#pragma unroll
    for (int j = 0; j < PF; ++j) {
        dl[j] = bf2f(delta[base + (size_t)j * ED]);
        xi[j] = bf2f(xin[base + (size_t)j * ED]);
        Bn[j] = dbc[(rb + j) * 80 + 48 + n];
        Cn[j] = dbc[(rb + j) * 80 + 64 + n];
        zz[j] = bf2f(zb[base + (size_t)j * ED]);
    }

    for (int l = 0; l < L_TOK; l += PF) {
#pragma unroll
        for (int j = 0; j < PF; ++j) {
            const int r = l + j;
            float cdl = dl[j], cxi = xi[j], cBn = Bn[j], cCn = Cn[j], cz = zz[j];
            const int rn = r + PF;
            if (rn < L_TOK) {   // uniform branch; refill slot j for step r+PF
                dl[j] = bf2f(delta[base + (size_t)rn * ED]);
                xi[j] = bf2f(xin[base + (size_t)rn * ED]);
                Bn[j] = dbc[(rb + rn) * 80 + 48 + n];
                Cn[j] = dbc[(rb + rn) * 80 + 64 + n];
                zz[j] = bf2f(zb[base + (size_t)rn * ED]);
            }
            float dA = __expf(cdl * a);
            h = dA * h + cdl * cxi * cBn;
            float p = h * cCn;
            p += __shfl_xor(p, 1);
            p += __shfl_xor(p, 2);
            p += __shfl_xor(p, 4);
            p += __shfl_xor(p, 8);
            if (n == 0) {
                float yv = p + dcf * cxi;
                float sz = cz / (1.f + __expf(-cz));
                y[base + (size_t)r * ED] = f2bf(yv * sz);
            }
        }
    }
}

// ----------------------------------------------------------------------------
// im2col for patch embed: P[r, k] (bf16) with r=(b, img, patch), k=(c,ph,pw)
// ----------------------------------------------------------------------------
__global__ __launch_bounds__(256)
void im2col_kernel(const float* __restrict__ rgb, const float* __restrict__ timg,
                   ushortT* __restrict__ P)
{
    int idx = blockIdx.x * 256 + threadIdx.x;
    if (idx >= ROWS * DM) return;
    int k = idx % DM;
    int r = idx / DM;
    int b = r / L_TOK;
    int l = r % L_TOK;
    const float* img = (l < 196) ? rgb : timg;
    int p  = (l < 196) ? l : l - 196;
    int py = p / 14, px = p % 14;
    int c  = k >> 8;
    int ph = (k >> 4) & 15;
    int pw = k & 15;
    P[idx] = f2bf(img[(((size_t)b * 3 + c) * 224 + (py * 16 + ph)) * 224 + (px * 16 + pw)]);
}

// ----------------------------------------------------------------------------
// Output: out[(l*768 + d)*8 + b] = x[b, l, d]
// ----------------------------------------------------------------------------
__global__ __launch_bounds__(256)
void out_transpose_kernel(const float* __restrict__ x, float* __restrict__ out)
{
    int idx = blockIdx.x * 256 + threadIdx.x;
    if (idx >= ROWS * DM) return;
    int b = idx & 7;
    int d = (idx >> 3) % DM;
    int l = idx / (8 * DM);
    out[idx] = x[((size_t)(b * L_TOK + l)) * DM + d];
}

// ----------------------------------------------------------------------------
extern "C" void kernel_launch(void* const* d_in, const int* in_sizes, int n_in,
                              void* d_out, int out_size, void* d_ws, size_t ws_size,
                              hipStream_t stream)
{
    (void)in_sizes; (void)n_in; (void)out_size; (void)ws_size;

    const float* rgb  = (const float*)d_in[0];
    const float* timg = (const float*)d_in[1];
    const float* pe_w = (const float*)d_in[2];   // [768, 3,16,16] -> [768][768]
    const float* pe_b = (const float*)d_in[3];
    const float* in_w = (const float*)d_in[4];   // [8, 3072, 768]
    const float* cw   = (const float*)d_in[5];   // [8, 1536, 1, 4]
    const float* cb   = (const float*)d_in[6];   // [8, 1536]
    const float* xw   = (const float*)d_in[7];   // [8, 80, 1536]
    const float* dtw  = (const float*)d_in[8];   // [8, 1536, 48]
    const float* dtb  = (const float*)d_in[9];   // [8, 1536]
    const float* alog = (const float*)d_in[10];  // [8, 1536, 16]
    const float* dvec = (const float*)d_in[11];  // [8, 1536]
    const float* ow   = (const float*)d_in[12];  // [8, 768, 1536]
    const float* nw   = (const float*)d_in[13];  // [8, 768]

    char* p = (char*)d_ws;
    float*   X   = (float*)p;    p += (size_t)ROWS * DM * 4;
    ushortT* XC  = (ushortT*)p;  p += (size_t)ROWS * ED * 2;   // conv-in / patches / y
    ushortT* Zb  = (ushortT*)p;  p += (size_t)ROWS * ED * 2;
    ushortT* XIN = (ushortT*)p;  p += (size_t)ROWS * ED * 2;
    ushortT* DEL = (ushortT*)p;  p += (size_t)ROWS * ED * 2;   // delta; front = xn
    float*   DBC = (float*)p;    p += (size_t)ROWS * 80 * 4;
    ushortT* XN  = DEL;          // overlay: xn dead before delta is written

    dim3 b256(256);
    const int MT = (ROWS + 127) / 128;   // 25 M-tiles

    // ---- patch embed: im2col (bf16) into XC, then MFMA GEMM+bias -> X ----
    im2col_kernel<<<(ROWS * DM + 255) / 256, b256, 0, stream>>>(rgb, timg, XC);
    gemm_mfma<EPI_BIAS, false><<<dim3(DM / 128, MT), b256, 0, stream>>>(
        XC, DM, pe_w, DM, pe_b, X, DM, ROWS, DM, DM);

    for (int i = 0; i < 8; ++i) {
        const float* in_wi = in_w + (size_t)i * 2 * ED * DM;
        const float* cwi   = cw   + (size_t)i * ED * 4;
        const float* cbi   = cb   + (size_t)i * ED;
        const float* xwi   = xw   + (size_t)i * 80 * ED;
        const float* dtwi  = dtw  + (size_t)i * ED * DTR;
        const float* dtbi  = dtb  + (size_t)i * ED;
        const float* ali   = alog + (size_t)i * ED * NST;
        const float* dvi   = dvec + (size_t)i * ED;
        const float* owi   = ow   + (size_t)i * DM * ED;
        const float* nwi   = nw   + (size_t)i * DM;

        // xn = rmsnorm(x)  -> XN (bf16, overlaid on DEL)
        rmsnorm_kernel<<<ROWS, b256, 0, stream>>>(X, nwi, XN);
        // xc = xn @ in_w[:ED]^T ; z = xn @ in_w[ED:]^T   (MFMA)
        gemm_mfma<EPI_STORE, true><<<dim3(ED / 128, MT), b256, 0, stream>>>(
            XN, DM, in_wi, DM, nullptr, XC, ED, ROWS, ED, DM);
        gemm_mfma<EPI_STORE, true><<<dim3(ED / 128, MT), b256, 0, stream>>>(
            XN, DM, in_wi + (size_t)ED * DM, DM, nullptr, Zb, ED, ROWS, ED, DM);
        // xin = silu(causal_conv(xc) + cb)
        conv_silu_kernel<<<(ROWS * ED + 255) / 256, b256, 0, stream>>>(
            XC, cwi, cbi, XIN);
        // dbc = xin @ xw^T  -> DBC fp32 [3136,80]   (VALU: N=80)
        gemm_nt<EPI_STORE, true, false><<<dim3(2, ROWS / 64), b256, 0, stream>>>(
            XIN, ED, xwi, ED, nullptr, DBC, 80, ROWS, 80, ED);
        // delta = softplus(dbc[:, :48] @ dtw^T + dtb) -> DEL bf16   (VALU: K=48)
        gemm_nt<EPI_BIAS_SOFTPLUS, false, true><<<dim3(ED / 64, ROWS / 64), b256, 0, stream>>>(
            DBC, 80, dtwi, DTR, dtbi, DEL, ED, ROWS, ED, DTR);
        // y = scan(...) fused +D*xin, *silu(z)  -> XC
        scan_kernel<<<BATCH * (ED / 16), b256, 0, stream>>>(
            DEL, XIN, DBC, Zb, ali, dvi, XC);
        // x += y @ ow^T   (MFMA)
        gemm_mfma<EPI_ADD, false><<<dim3(DM / 128, MT), b256, 0, stream>>>(
            XC, ED, owi, ED, nullptr, X, DM, ROWS, DM, ED);
    }

    out_transpose_kernel<<<(ROWS * DM + 255) / 256, b256, 0, stream>>>(
        X, (float*)d_out);
}

// Round 5
// 2867.087 us; speedup vs baseline: 1.5702x; 1.5702x over previous
//
#include <hip/hip_runtime.h>
#include <cstddef>
#include <cstdint>

// ---- model dims ----
#define L_TOK 392
#define BATCH 8
#define DM    768
#define ED    1536
#define NST   16
#define DTR   48
#define ROWS  (BATCH * L_TOK)   // 3136

// chunked scan
#define C_CH 8
#define CLEN 49                 // L_TOK / C_CH, 49 = 7*7 -> ring depth 7
#define EGB  24                 // ED/64 e-groups (64-thread blocks)

// Workspace layout unchanged from round 2/3 (~47 MB; round-1 overran at 107MB
// and corrupted pristine inputs -- do NOT grow d_ws).  Chunk-scan scratch
// (6.7 MB: HEND + SDL) lives in d_out, which is dead until out_transpose.

typedef unsigned short ushortT;
typedef __bf16 bf16x8 __attribute__((ext_vector_type(8)));
typedef unsigned short us8 __attribute__((ext_vector_type(8)));
typedef unsigned short us4 __attribute__((ext_vector_type(4)));
typedef float f32x4 __attribute__((ext_vector_type(4)));

__device__ __forceinline__ float bf2f(ushortT u) {
    union { unsigned int i; float f; } v; v.i = ((unsigned int)u) << 16; return v.f;
}
__device__ __forceinline__ ushortT f2bf(float f) {
    union { float f; unsigned int i; } v; v.f = f;
    unsigned int r = v.i + 0x7FFFu + ((v.i >> 16) & 1u);   // round-nearest-even
    return (ushortT)(r >> 16);
}

enum { EPI_STORE = 0, EPI_BIAS = 1, EPI_BIAS_SOFTPLUS = 2, EPI_ADD = 3 };

// ----------------------------------------------------------------------------
// MFMA GEMM: C[M,N] (epi)= A[M,K](bf16, lda) @ W[N,K](fp32, ldw)^T
// 128x128 tile, BK=32, 256 threads = 4 waves in 2x2, each wave 64x64 via
// 4x4 v_mfma_f32_16x16x32_bf16.  W converted fp32->bf16 during LDS staging.
// ----------------------------------------------------------------------------
template <int EPI, bool C_BF>
__global__ __launch_bounds__(256)
void gemm_mfma(const ushortT* __restrict__ A, int lda,
               const float* __restrict__ W, int ldw,
               const float* __restrict__ bias,
               void* __restrict__ Cv, int ldc,
               int M, int N, int K)
{
    __shared__ ushortT As[128 * 40];
    __shared__ ushortT Ws[128 * 40];

    const int tid  = threadIdx.x;
    const int lane = tid & 63;
    const int wave = tid >> 6;
    const int wm   = wave >> 1;        // 0..1
    const int wn   = wave & 1;         // 0..1
    const int quad = lane >> 4;        // 0..3
    const int l16  = lane & 15;        // 0..15

    const int m0 = blockIdx.y * 128;
    const int n0 = blockIdx.x * 128;

    const int ar   = tid >> 1;         // 0..127  A row
    const int ahalf= tid & 1;          // 16-elem half
    const int wr   = tid >> 3;         // 0..31   W row (x4 iters)
    const int wc   = (tid & 7) * 4;    // float4 col

    f32x4 acc[4][4] = {};

    for (int k0 = 0; k0 < K; k0 += 32) {
        us8 a0 = {0,0,0,0,0,0,0,0}, a1 = {0,0,0,0,0,0,0,0};
        int gm = m0 + ar;
        if (gm < M) {
            const ushortT* src = A + (size_t)gm * lda + k0 + ahalf * 16;
            a0 = *(const us8*)(src);
            a1 = *(const us8*)(src + 8);
        }
        *(us8*)&As[ar * 40 + ahalf * 16]     = a0;
        *(us8*)&As[ar * 40 + ahalf * 16 + 8] = a1;
#pragma unroll
        for (int it = 0; it < 4; ++it) {
            int row = it * 32 + wr;
            float4 f = *(const float4*)(W + (size_t)(n0 + row) * ldw + k0 + wc);
            us4 h; h.x = f2bf(f.x); h.y = f2bf(f.y); h.z = f2bf(f.z); h.w = f2bf(f.w);
            *(us4*)&Ws[row * 40 + wc] = h;
        }
        __syncthreads();

        bf16x8 af[4], bw[4];
#pragma unroll
        for (int t = 0; t < 4; ++t) {
            us8 ta = *(const us8*)&As[(wm * 64 + t * 16 + l16) * 40 + quad * 8];
            af[t] = __builtin_bit_cast(bf16x8, ta);
            us8 tb = *(const us8*)&Ws[(wn * 64 + t * 16 + l16) * 40 + quad * 8];
            bw[t] = __builtin_bit_cast(bf16x8, tb);
        }
#pragma unroll
        for (int i = 0; i < 4; ++i)
#pragma unroll
            for (int j = 0; j < 4; ++j)
                acc[i][j] = __builtin_amdgcn_mfma_f32_16x16x32_bf16(
                    af[i], bw[j], acc[i][j], 0, 0, 0);
        __syncthreads();
    }

#pragma unroll
    for (int i = 0; i < 4; ++i) {
#pragma unroll
        for (int r = 0; r < 4; ++r) {
            int gm = m0 + wm * 64 + i * 16 + quad * 4 + r;
            if (gm >= M) continue;
#pragma unroll
            for (int j = 0; j < 4; ++j) {
                int gn = n0 + wn * 64 + j * 16 + l16;
                float v = acc[i][j][r];
                if (EPI == EPI_BIAS) v += bias[gn];
                size_t off = (size_t)gm * ldc + gn;
                if (C_BF) {
                    ((ushortT*)Cv)[off] = f2bf(v);
                } else {
                    float* p = (float*)Cv + off;
                    *p = (EPI == EPI_ADD) ? v + *p : v;
                }
            }
        }
    }
}

// ----------------------------------------------------------------------------
// VALU tiled GEMM for the small shapes (x_proj N=80, dt_proj K=48).
// ----------------------------------------------------------------------------
template <int EPI, bool A_BF, bool C_BF>
__global__ __launch_bounds__(256)
void gemm_nt(const void* __restrict__ Av, int lda,
             const float* __restrict__ W, int ldw,
             const float* __restrict__ bias,
             void* __restrict__ Cv, int ldc,
             int M, int N, int K)
{
    __shared__ float As[16][68];
    __shared__ float Bs[16][68];
    const int tid = threadIdx.x;
    const int tx  = tid & 15;
    const int ty  = tid >> 4;
    const int bm  = blockIdx.y * 64;
    const int bn  = blockIdx.x * 64;
    const int lr  = tid >> 2;
    const int lk  = (tid & 3) * 4;

    float acc[4][4] = {};

    for (int k0 = 0; k0 < K; k0 += 16) {
        float a0 = 0.f, a1 = 0.f, a2 = 0.f, a3 = 0.f;
        float w0 = 0.f, w1 = 0.f, w2 = 0.f, w3 = 0.f;
        int ga = bm + lr;
        if (ga < M) {
            if (A_BF) {
                const ushortT* A = (const ushortT*)Av;
                ushort4 t = *(const ushort4*)(A + (size_t)ga * lda + k0 + lk);
                a0 = bf2f(t.x); a1 = bf2f(t.y); a2 = bf2f(t.z); a3 = bf2f(t.w);
            } else {
                const float* A = (const float*)Av;
                float4 t = *(const float4*)(A + (size_t)ga * lda + k0 + lk);
                a0 = t.x; a1 = t.y; a2 = t.z; a3 = t.w;
            }
        }
        int gw = bn + lr;
        if (gw < N) {
            float4 t = *(const float4*)(W + (size_t)gw * ldw + k0 + lk);
            w0 = t.x; w1 = t.y; w2 = t.z; w3 = t.w;
        }
        As[lk + 0][lr] = a0; As[lk + 1][lr] = a1;
        As[lk + 2][lr] = a2; As[lk + 3][lr] = a3;
        Bs[lk + 0][lr] = w0; Bs[lk + 1][lr] = w1;
        Bs[lk + 2][lr] = w2; Bs[lk + 3][lr] = w3;
        __syncthreads();
#pragma unroll
        for (int k = 0; k < 16; ++k) {
            float4 a4 = *(const float4*)&As[k][ty * 4];
            float4 b4 = *(const float4*)&Bs[k][tx * 4];
            float a[4] = {a4.x, a4.y, a4.z, a4.w};
            float b[4] = {b4.x, b4.y, b4.z, b4.w};
#pragma unroll
            for (int i = 0; i < 4; ++i)
#pragma unroll
                for (int j = 0; j < 4; ++j)
                    acc[i][j] += a[i] * b[j];
        }
        __syncthreads();
    }

#pragma unroll
    for (int i = 0; i < 4; ++i) {
        int gm = bm + ty * 4 + i;
        if (gm >= M) continue;
#pragma unroll
        for (int j = 0; j < 4; ++j) {
            int gn = bn + tx * 4 + j;
            if (gn >= N) continue;
            float v = acc[i][j];
            if (EPI == EPI_BIAS) v += bias[gn];
            if (EPI == EPI_BIAS_SOFTPLUS) {
                v += bias[gn];
                v = fmaxf(v, 0.f) + log1pf(expf(-fabsf(v)));  // softplus
            }
            size_t off = (size_t)gm * ldc + gn;
            if (C_BF) {
                ((ushortT*)Cv)[off] = f2bf(v);
            } else {
                float* p = (float*)Cv + off;
                *p = (EPI == EPI_ADD) ? v + *p : v;
            }
        }
    }
}

// ----------------------------------------------------------------------------
// RMSNorm: xn[r,:] = x[r,:] * rsqrt(mean(x^2)+1e-5) * w   (768/row, bf16 out)
// ----------------------------------------------------------------------------
__global__ __launch_bounds__(256)
void rmsnorm_kernel(const float* __restrict__ x, const float* __restrict__ w,
                    ushortT* __restrict__ xn)
{
    int r = blockIdx.x;
    const float* xr = x + (size_t)r * DM;
    float v[3];
    float s = 0.f;
#pragma unroll
    for (int i = 0; i < 3; ++i) {
        v[i] = xr[threadIdx.x + i * 256];
        s += v[i] * v[i];
    }
#pragma unroll
    for (int o = 32; o > 0; o >>= 1) s += __shfl_down(s, o, 64);
    __shared__ float wsum[4];
    __shared__ float scale_s;
    int wave = threadIdx.x >> 6;
    if ((threadIdx.x & 63) == 0) wsum[wave] = s;
    __syncthreads();
    if (threadIdx.x == 0) {
        float t = wsum[0] + wsum[1] + wsum[2] + wsum[3];
        scale_s = rsqrtf(t * (1.f / 768.f) + 1e-5f);
    }
    __syncthreads();
    float sc = scale_s;
#pragma unroll
    for (int i = 0; i < 3; ++i) {
        int d = threadIdx.x + i * 256;
        xn[(size_t)r * DM + d] = f2bf(v[i] * sc * w[d]);
    }
}

// ----------------------------------------------------------------------------
// Causal depthwise conv (width 4) + bias + silu.
// ----------------------------------------------------------------------------
__global__ __launch_bounds__(256)
void conv_silu_kernel(const ushortT* __restrict__ xc, const float* __restrict__ cw,
                      const float* __restrict__ cb, ushortT* __restrict__ xin)
{
    int idx = blockIdx.x * 256 + threadIdx.x;
    if (idx >= ROWS * ED) return;
    int e = idx % ED;
    int r = idx / ED;
    int l = r % L_TOK;
    float w0 = cw[e * 4 + 0], w1 = cw[e * 4 + 1];
    float w2 = cw[e * 4 + 2], w3 = cw[e * 4 + 3];
    const ushortT* base = xc + (size_t)r * ED + e;
    float acc = cb[e] + w3 * bf2f(base[0]);
    if (l >= 1) acc += w2 * bf2f(base[-(ptrdiff_t)ED]);
    if (l >= 2) acc += w1 * bf2f(base[-(ptrdiff_t)(2 * ED)]);
    if (l >= 3) acc += w0 * bf2f(base[-(ptrdiff_t)(3 * ED)]);
    xin[(size_t)r * ED + e] = f2bf(acc / (1.f + __expf(-acc)));  // silu
}

// ----------------------------------------------------------------------------
// Chunked selective scan, pass 1: per (b,e,chunk) compute the chunk's local
// end-state h_end[16] (from h=0) and sum_delta (prod dA == exp(a*sum_delta)).
// One thread per (b,e); 16 states in registers -> no shuffles, ~2.5 ops/state.
// 64-thread blocks; grid 8*8*24 = 1536 = 6 blocks/CU exactly.
// ----------------------------------------------------------------------------
__global__ __launch_bounds__(64)
void scan_part1(const ushortT* __restrict__ delta, const ushortT* __restrict__ xin,
                const float* __restrict__ dbc, const float* __restrict__ a_log,
                float* __restrict__ hend, float* __restrict__ sdl)
{
    __shared__ float BsL[CLEN * 16];
    const int tid = threadIdx.x;
    const int bid = blockIdx.x;
    const int eg = bid % EGB;
    const int c  = (bid / EGB) % C_CH;
    const int b  = bid / (EGB * C_CH);
    const int e  = eg * 64 + tid;
    const int l0 = c * CLEN;
    const int rb = b * L_TOK + l0;

    for (int i = tid; i < CLEN * 16; i += 64) {
        int s = i >> 4, n = i & 15;
        BsL[i] = dbc[(size_t)(rb + s) * 80 + 48 + n];
    }
    __syncthreads();

    float a[16];
    const float* ar = a_log + (size_t)e * 16;
#pragma unroll
    for (int n = 0; n < 16; ++n) a[n] = -__expf(ar[n]);

    float h[16];
#pragma unroll
    for (int n = 0; n < 16; ++n) h[n] = 0.f;
    float sum_dl = 0.f;

    const size_t base = (size_t)rb * ED + e;
    float rdl[7], rxi[7];
#pragma unroll
    for (int j = 0; j < 7; ++j) {
        rdl[j] = bf2f(delta[base + (size_t)j * ED]);
        rxi[j] = bf2f(xin[base + (size_t)j * ED]);
    }
    for (int s0 = 0; s0 < CLEN; s0 += 7) {
#pragma unroll
        for (int j = 0; j < 7; ++j) {
            const int s = s0 + j;
            float dl = rdl[j], xi = rxi[j];
            int sp = s + 7; if (sp > CLEN - 1) sp = CLEN - 1;   // clamped prefetch
            rdl[j] = bf2f(delta[base + (size_t)sp * ED]);
            rxi[j] = bf2f(xin[base + (size_t)sp * ED]);
            float dlxi = dl * xi;
            sum_dl += dl;
#pragma unroll
            for (int n = 0; n < 16; ++n)
                h[n] = __expf(dl * a[n]) * h[n] + dlxi * BsL[s * 16 + n];
        }
    }

    float* hp = hend + (((size_t)b * ED + e) * C_CH + c) * 16;
#pragma unroll
    for (int n = 0; n < 16; ++n) hp[n] = h[n];
    sdl[((size_t)b * ED + e) * C_CH + c] = sum_dl;
}

// ----------------------------------------------------------------------------
// Chunked scan, pass 2: combine predecessor chunk summaries into the chunk's
// start state, then re-run the chunk emitting y (+D*xin, *silu(z) fused).
// ----------------------------------------------------------------------------
__global__ __launch_bounds__(64)
void scan_part2(const ushortT* __restrict__ delta, const ushortT* __restrict__ xin,
                const float* __restrict__ dbc, const ushortT* __restrict__ zb,
                const float* __restrict__ a_log, const float* __restrict__ dvec,
                const float* __restrict__ hend, const float* __restrict__ sdl,
                ushortT* __restrict__ y)
{
    __shared__ float BsL[CLEN * 16];
    __shared__ float CsL[CLEN * 16];
    const int tid = threadIdx.x;
    const int bid = blockIdx.x;
    const int eg = bid % EGB;
    const int c  = (bid / EGB) % C_CH;
    const int b  = bid / (EGB * C_CH);
    const int e  = eg * 64 + tid;
    const int l0 = c * CLEN;
    const int rb = b * L_TOK + l0;

    for (int i = tid; i < CLEN * 16; i += 64) {
        int s = i >> 4, n = i & 15;
        size_t row = (size_t)(rb + s) * 80;
        BsL[i] = dbc[row + 48 + n];
        CsL[i] = dbc[row + 64 + n];
    }
    __syncthreads();

    float a[16];
    const float* ar = a_log + (size_t)e * 16;
#pragma unroll
    for (int n = 0; n < 16; ++n) a[n] = -__expf(ar[n]);
    const float dcf = dvec[e];

    // carry-in: combine chunk summaries 0..c-1
    float h[16];
#pragma unroll
    for (int n = 0; n < 16; ++n) h[n] = 0.f;
    const float* hb = hend + (((size_t)b * ED + e) * C_CH) * 16;
    const float* sb = sdl + ((size_t)b * ED + e) * C_CH;
    for (int cc = 0; cc < c; ++cc) {
        float sv = sb[cc];
#pragma unroll
        for (int n = 0; n < 16; ++n)
            h[n] = __expf(a[n] * sv) * h[n] + hb[cc * 16 + n];
    }

    const size_t base = (size_t)rb * ED + e;
    float rdl[7], rxi[7], rz[7];
#pragma unroll
    for (int j = 0; j < 7; ++j) {
        rdl[j] = bf2f(delta[base + (size_t)j * ED]);
        rxi[j] = bf2f(xin[base + (size_t)j * ED]);
        rz[j]  = bf2f(zb[base + (size_t)j * ED]);
    }
    for (int s0 = 0; s0 < CLEN; s0 += 7) {
#pragma unroll
        for (int j = 0; j < 7; ++j) {
            const int s = s0 + j;
            float dl = rdl[j], xi = rxi[j], z = rz[j];
            int sp = s + 7; if (sp > CLEN - 1) sp = CLEN - 1;   // clamped prefetch
            rdl[j] = bf2f(delta[base + (size_t)sp * ED]);
            rxi[j] = bf2f(xin[base + (size_t)sp * ED]);
            rz[j]  = bf2f(zb[base + (size_t)sp * ED]);
            float dlxi = dl * xi;
            float yv = 0.f;
#pragma unroll
            for (int n = 0; n < 16; ++n) {
                h[n] = __expf(dl * a[n]) * h[n] + dlxi * BsL[s * 16 + n];
                yv += h[n] * CsL[s * 16 + n];
            }
            yv += dcf * xi;
            float sz = z / (1.f + __expf(-z));
            y[base + (size_t)s * ED] = f2bf(yv * sz);
        }
    }
}

// ----------------------------------------------------------------------------
// im2col for patch embed: P[r, k] (bf16) with r=(b, img, patch), k=(c,ph,pw)
// ----------------------------------------------------------------------------
__global__ __launch_bounds__(256)
void im2col_kernel(const float* __restrict__ rgb, const float* __restrict__ timg,
                   ushortT* __restrict__ P)
{
    int idx = blockIdx.x * 256 + threadIdx.x;
    if (idx >= ROWS * DM) return;
    int k = idx % DM;
    int r = idx / DM;
    int b = r / L_TOK;
    int l = r % L_TOK;
    const float* img = (l < 196) ? rgb : timg;
    int p  = (l < 196) ? l : l - 196;
    int py = p / 14, px = p % 14;
    int c  = k >> 8;
    int ph = (k >> 4) & 15;
    int pw = k & 15;
    P[idx] = f2bf(img[(((size_t)b * 3 + c) * 224 + (py * 16 + ph)) * 224 + (px * 16 + pw)]);
}

// ----------------------------------------------------------------------------
// Output: out[(l*768 + d)*8 + b] = x[b, l, d]
// ----------------------------------------------------------------------------
__global__ __launch_bounds__(256)
void out_transpose_kernel(const float* __restrict__ x, float* __restrict__ out)
{
    int idx = blockIdx.x * 256 + threadIdx.x;
    if (idx >= ROWS * DM) return;
    int b = idx & 7;
    int d = (idx >> 3) % DM;
    int l = idx / (8 * DM);
    out[idx] = x[((size_t)(b * L_TOK + l)) * DM + d];
}

// ----------------------------------------------------------------------------
extern "C" void kernel_launch(void* const* d_in, const int* in_sizes, int n_in,
                              void* d_out, int out_size, void* d_ws, size_t ws_size,
                              hipStream_t stream)
{
    (void)in_sizes; (void)n_in; (void)out_size; (void)ws_size;

    const float* rgb  = (const float*)d_in[0];
    const float* timg = (const float*)d_in[1];
    const float* pe_w = (const float*)d_in[2];   // [768, 3,16,16] -> [768][768]
    const float* pe_b = (const float*)d_in[3];
    const float* in_w = (const float*)d_in[4];   // [8, 3072, 768]
    const float* cw   = (const float*)d_in[5];   // [8, 1536, 1, 4]
    const float* cb   = (const float*)d_in[6];   // [8, 1536]
    const float* xw   = (const float*)d_in[7];   // [8, 80, 1536]
    const float* dtw  = (const float*)d_in[8];   // [8, 1536, 48]
    const float* dtb  = (const float*)d_in[9];   // [8, 1536]
    const float* alog = (const float*)d_in[10];  // [8, 1536, 16]
    const float* dvec = (const float*)d_in[11];  // [8, 1536]
    const float* ow   = (const float*)d_in[12];  // [8, 768, 1536]
    const float* nw   = (const float*)d_in[13];  // [8, 768]

    char* p = (char*)d_ws;
    float*   X   = (float*)p;    p += (size_t)ROWS * DM * 4;
    ushortT* XC  = (ushortT*)p;  p += (size_t)ROWS * ED * 2;   // conv-in / patches / y
    ushortT* Zb  = (ushortT*)p;  p += (size_t)ROWS * ED * 2;
    ushortT* XIN = (ushortT*)p;  p += (size_t)ROWS * ED * 2;
    ushortT* DEL = (ushortT*)p;  p += (size_t)ROWS * ED * 2;   // delta; front = xn
    float*   DBC = (float*)p;    p += (size_t)ROWS * 80 * 4;
    ushortT* XN  = DEL;          // overlay: xn dead before delta is written

    // chunk-scan scratch lives in d_out (dead until out_transpose):
    //   HEND: B*ED*C_CH*16 = 1,572,864 floats; SDL: 98,304 floats
    //   total 1,671,168 < out_size (2,408,448)
    float* HEND = (float*)d_out;
    float* SDL  = HEND + (size_t)BATCH * ED * C_CH * 16;

    dim3 b256(256);
    const int MT = (ROWS + 127) / 128;   // 25 M-tiles
    const int SCAN_BLOCKS = BATCH * C_CH * EGB;   // 1536

    // ---- patch embed: im2col (bf16) into XC, then MFMA GEMM+bias -> X ----
    im2col_kernel<<<(ROWS * DM + 255) / 256, b256, 0, stream>>>(rgb, timg, XC);
    gemm_mfma<EPI_BIAS, false><<<dim3(DM / 128, MT), b256, 0, stream>>>(
        XC, DM, pe_w, DM, pe_b, X, DM, ROWS, DM, DM);

    for (int i = 0; i < 8; ++i) {
        const float* in_wi = in_w + (size_t)i * 2 * ED * DM;
        const float* cwi   = cw   + (size_t)i * ED * 4;
        const float* cbi   = cb   + (size_t)i * ED;
        const float* xwi   = xw   + (size_t)i * 80 * ED;
        const float* dtwi  = dtw  + (size_t)i * ED * DTR;
        const float* dtbi  = dtb  + (size_t)i * ED;
        const float* ali   = alog + (size_t)i * ED * NST;
        const float* dvi   = dvec + (size_t)i * ED;
        const float* owi   = ow   + (size_t)i * DM * ED;
        const float* nwi   = nw   + (size_t)i * DM;

        // xn = rmsnorm(x)  -> XN (bf16, overlaid on DEL)
        rmsnorm_kernel<<<ROWS, b256, 0, stream>>>(X, nwi, XN);
        // xc = xn @ in_w[:ED]^T ; z = xn @ in_w[ED:]^T   (MFMA)
        gemm_mfma<EPI_STORE, true><<<dim3(ED / 128, MT), b256, 0, stream>>>(
            XN, DM, in_wi, DM, nullptr, XC, ED, ROWS, ED, DM);
        gemm_mfma<EPI_STORE, true><<<dim3(ED / 128, MT), b256, 0, stream>>>(
            XN, DM, in_wi + (size_t)ED * DM, DM, nullptr, Zb, ED, ROWS, ED, DM);
        // xin = silu(causal_conv(xc) + cb)
        conv_silu_kernel<<<(ROWS * ED + 255) / 256, b256, 0, stream>>>(
            XC, cwi, cbi, XIN);
        // dbc = xin @ xw^T  -> DBC fp32 [3136,80]   (VALU: N=80)
        gemm_nt<EPI_STORE, true, false><<<dim3(2, ROWS / 64), b256, 0, stream>>>(
            XIN, ED, xwi, ED, nullptr, DBC, 80, ROWS, 80, ED);
        // delta = softplus(dbc[:, :48] @ dtw^T + dtb) -> DEL bf16   (VALU: K=48)
        gemm_nt<EPI_BIAS_SOFTPLUS, false, true><<<dim3(ED / 64, ROWS / 64), b256, 0, stream>>>(
            DBC, 80, dtwi, DTR, dtbi, DEL, ED, ROWS, ED, DTR);
        // chunked scan: pass1 summaries -> pass2 seeded scan + y  -> XC
        scan_part1<<<SCAN_BLOCKS, 64, 0, stream>>>(
            DEL, XIN, DBC, ali, HEND, SDL);
        scan_part2<<<SCAN_BLOCKS, 64, 0, stream>>>(
            DEL, XIN, DBC, Zb, ali, dvi, HEND, SDL, XC);
        // x += y @ ow^T   (MFMA)
        gemm_mfma<EPI_ADD, false><<<dim3(DM / 128, MT), b256, 0, stream>>>(
            XC, ED, owi, ED, nullptr, X, DM, ROWS, DM, ED);
    }

    out_transpose_kernel<<<(ROWS * DM + 255) / 256, b256, 0, stream>>>(
        X, (float*)d_out);
}

// Round 6
// 2226.490 us; speedup vs baseline: 2.0220x; 1.2877x over previous
//
#include <hip/hip_runtime.h>
#include <cstddef>
#include <cstdint>

// ---- model dims ----
#define L_TOK 392
#define BATCH 8
#define DM    768
#define ED    1536
#define NST   16
#define DTR   48
#define ROWS  (BATCH * L_TOK)   // 3136

// chunked scan
#define C_CH 8
#define CLEN 49                 // L_TOK / C_CH
#define EGB  24                 // ED/64 e-groups

// Workspace ~47 MB (round-1 overran at 107MB and corrupted pristine inputs --
// do NOT grow d_ws). Chunk-scan scratch lives in d_out (dead until transpose).

typedef unsigned short ushortT;
typedef __bf16 bf16x8 __attribute__((ext_vector_type(8)));
typedef unsigned short us8 __attribute__((ext_vector_type(8)));
typedef unsigned short us4 __attribute__((ext_vector_type(4)));
typedef float f32x4 __attribute__((ext_vector_type(4)));

__device__ __forceinline__ float bf2f(ushortT u) {
    union { unsigned int i; float f; } v; v.i = ((unsigned int)u) << 16; return v.f;
}
__device__ __forceinline__ ushortT f2bf(float f) {
    union { float f; unsigned int i; } v; v.f = f;
    unsigned int r = v.i + 0x7FFFu + ((v.i >> 16) & 1u);   // round-nearest-even
    return (ushortT)(r >> 16);
}

enum { EPI_STORE = 0, EPI_BIAS = 1, EPI_BIAS_SOFTPLUS = 2, EPI_ADD = 3 };

// ----------------------------------------------------------------------------
// MFMA GEMM: C[M,N] (epi)= A[M,K](bf16, lda) @ W[N,K](fp32, ldw)^T
// 128x128 tile, BK=32, 256 threads = 4 waves in 2x2, each wave 64x64 via
// 4x4 v_mfma_f32_16x16x32_bf16.  W converted fp32->bf16 during LDS staging.
// SPLIT: block-uniform output split at column ED (in_proj writes XC | Zb).
// ----------------------------------------------------------------------------
template <int EPI, bool C_BF, bool SPLIT>
__global__ __launch_bounds__(256)
void gemm_mfma(const ushortT* __restrict__ A, int lda,
               const float* __restrict__ W, int ldw,
               const float* __restrict__ bias,
               void* __restrict__ Cv, void* __restrict__ Cv2, int ldc,
               int M, int N, int K)
{
    __shared__ ushortT As[128 * 40];
    __shared__ ushortT Ws[128 * 40];

    const int tid  = threadIdx.x;
    const int lane = tid & 63;
    const int wave = tid >> 6;
    const int wm   = wave >> 1;        // 0..1
    const int wn   = wave & 1;         // 0..1
    const int quad = lane >> 4;        // 0..3
    const int l16  = lane & 15;        // 0..15

    const int m0 = blockIdx.y * 128;
    const int n0 = blockIdx.x * 128;

    const int ar   = tid >> 1;         // 0..127  A row
    const int ahalf= tid & 1;          // 16-elem half
    const int wr   = tid >> 3;         // 0..31   W row (x4 iters)
    const int wc   = (tid & 7) * 4;    // float4 col

    f32x4 acc[4][4] = {};

    for (int k0 = 0; k0 < K; k0 += 32) {
        us8 a0 = {0,0,0,0,0,0,0,0}, a1 = {0,0,0,0,0,0,0,0};
        int gm = m0 + ar;
        if (gm < M) {
            const ushortT* src = A + (size_t)gm * lda + k0 + ahalf * 16;
            a0 = *(const us8*)(src);
            a1 = *(const us8*)(src + 8);
        }
        *(us8*)&As[ar * 40 + ahalf * 16]     = a0;
        *(us8*)&As[ar * 40 + ahalf * 16 + 8] = a1;
#pragma unroll
        for (int it = 0; it < 4; ++it) {
            int row = it * 32 + wr;
            float4 f = *(const float4*)(W + (size_t)(n0 + row) * ldw + k0 + wc);
            us4 h; h.x = f2bf(f.x); h.y = f2bf(f.y); h.z = f2bf(f.z); h.w = f2bf(f.w);
            *(us4*)&Ws[row * 40 + wc] = h;
        }
        __syncthreads();

        bf16x8 af[4], bw[4];
#pragma unroll
        for (int t = 0; t < 4; ++t) {
            us8 ta = *(const us8*)&As[(wm * 64 + t * 16 + l16) * 40 + quad * 8];
            af[t] = __builtin_bit_cast(bf16x8, ta);
            us8 tb = *(const us8*)&Ws[(wn * 64 + t * 16 + l16) * 40 + quad * 8];
            bw[t] = __builtin_bit_cast(bf16x8, tb);
        }
#pragma unroll
        for (int i = 0; i < 4; ++i)
#pragma unroll
            for (int j = 0; j < 4; ++j)
                acc[i][j] = __builtin_amdgcn_mfma_f32_16x16x32_bf16(
                    af[i], bw[j], acc[i][j], 0, 0, 0);
        __syncthreads();
    }

#pragma unroll
    for (int i = 0; i < 4; ++i) {
#pragma unroll
        for (int r = 0; r < 4; ++r) {
            int gm = m0 + wm * 64 + i * 16 + quad * 4 + r;
            if (gm >= M) continue;
#pragma unroll
            for (int j = 0; j < 4; ++j) {
                int gn = n0 + wn * 64 + j * 16 + l16;
                float v = acc[i][j][r];
                if (EPI == EPI_BIAS) v += bias[gn];
                void* dst = Cv;
                int cn = gn;
                if (SPLIT && gn >= ED) { dst = Cv2; cn = gn - ED; }  // block-uniform
                size_t off = (size_t)gm * ldc + cn;
                if (C_BF) {
                    ((ushortT*)dst)[off] = f2bf(v);
                } else {
                    float* p = (float*)dst + off;
                    *p = (EPI == EPI_ADD) ? v + *p : v;
                }
            }
        }
    }
}

// ----------------------------------------------------------------------------
// Split-K VALU GEMM for x_proj (N=80): C[M,N] += A[M,K] @ W[N,K]^T over a
// K-chunk per blockIdx.z; fp32 atomicAdd epilogue (C pre-zeroed).
// Fixes the round-5 occupancy bug: 98 blocks -> 784 blocks.
// ----------------------------------------------------------------------------
__global__ __launch_bounds__(256)
void gemm_nt_splitk(const ushortT* __restrict__ A, int lda,
                    const float* __restrict__ W, int ldw,
                    float* __restrict__ C, int ldc,
                    int M, int N, int K, int kchunk)
{
    __shared__ float As[16][68];
    __shared__ float Bs[16][68];
    const int tid = threadIdx.x;
    const int tx  = tid & 15;
    const int ty  = tid >> 4;
    const int bm  = blockIdx.y * 64;
    const int bn  = blockIdx.x * 64;
    const int lr  = tid >> 2;
    const int lk  = (tid & 3) * 4;
    const int kb  = blockIdx.z * kchunk;
    const int ke  = kb + kchunk;

    float acc[4][4] = {};

    for (int k0 = kb; k0 < ke; k0 += 16) {
        float a0 = 0.f, a1 = 0.f, a2 = 0.f, a3 = 0.f;
        float w0 = 0.f, w1 = 0.f, w2 = 0.f, w3 = 0.f;
        int ga = bm + lr;
        if (ga < M) {
            ushort4 t = *(const ushort4*)(A + (size_t)ga * lda + k0 + lk);
            a0 = bf2f(t.x); a1 = bf2f(t.y); a2 = bf2f(t.z); a3 = bf2f(t.w);
        }
        int gw = bn + lr;
        if (gw < N) {
            float4 t = *(const float4*)(W + (size_t)gw * ldw + k0 + lk);
            w0 = t.x; w1 = t.y; w2 = t.z; w3 = t.w;
        }
        As[lk + 0][lr] = a0; As[lk + 1][lr] = a1;
        As[lk + 2][lr] = a2; As[lk + 3][lr] = a3;
        Bs[lk + 0][lr] = w0; Bs[lk + 1][lr] = w1;
        Bs[lk + 2][lr] = w2; Bs[lk + 3][lr] = w3;
        __syncthreads();
#pragma unroll
        for (int k = 0; k < 16; ++k) {
            float4 a4 = *(const float4*)&As[k][ty * 4];
            float4 b4 = *(const float4*)&Bs[k][tx * 4];
            float a[4] = {a4.x, a4.y, a4.z, a4.w};
            float b[4] = {b4.x, b4.y, b4.z, b4.w};
#pragma unroll
            for (int i = 0; i < 4; ++i)
#pragma unroll
                for (int j = 0; j < 4; ++j)
                    acc[i][j] += a[i] * b[j];
        }
        __syncthreads();
    }

#pragma unroll
    for (int i = 0; i < 4; ++i) {
        int gm = bm + ty * 4 + i;
        if (gm >= M) continue;
#pragma unroll
        for (int j = 0; j < 4; ++j) {
            int gn = bn + tx * 4 + j;
            if (gn >= N) continue;
            atomicAdd(C + (size_t)gm * ldc + gn, acc[i][j]);
        }
    }
}

// ----------------------------------------------------------------------------
// VALU tiled GEMM (dt_proj: K=48).
// ----------------------------------------------------------------------------
template <int EPI, bool A_BF, bool C_BF>
__global__ __launch_bounds__(256)
void gemm_nt(const void* __restrict__ Av, int lda,
             const float* __restrict__ W, int ldw,
             const float* __restrict__ bias,
             void* __restrict__ Cv, int ldc,
             int M, int N, int K)
{
    __shared__ float As[16][68];
    __shared__ float Bs[16][68];
    const int tid = threadIdx.x;
    const int tx  = tid & 15;
    const int ty  = tid >> 4;
    const int bm  = blockIdx.y * 64;
    const int bn  = blockIdx.x * 64;
    const int lr  = tid >> 2;
    const int lk  = (tid & 3) * 4;

    float acc[4][4] = {};

    for (int k0 = 0; k0 < K; k0 += 16) {
        float a0 = 0.f, a1 = 0.f, a2 = 0.f, a3 = 0.f;
        float w0 = 0.f, w1 = 0.f, w2 = 0.f, w3 = 0.f;
        int ga = bm + lr;
        if (ga < M) {
            if (A_BF) {
                const ushortT* A = (const ushortT*)Av;
                ushort4 t = *(const ushort4*)(A + (size_t)ga * lda + k0 + lk);
                a0 = bf2f(t.x); a1 = bf2f(t.y); a2 = bf2f(t.z); a3 = bf2f(t.w);
            } else {
                const float* A = (const float*)Av;
                float4 t = *(const float4*)(A + (size_t)ga * lda + k0 + lk);
                a0 = t.x; a1 = t.y; a2 = t.z; a3 = t.w;
            }
        }
        int gw = bn + lr;
        if (gw < N) {
            float4 t = *(const float4*)(W + (size_t)gw * ldw + k0 + lk);
            w0 = t.x; w1 = t.y; w2 = t.z; w3 = t.w;
        }
        As[lk + 0][lr] = a0; As[lk + 1][lr] = a1;
        As[lk + 2][lr] = a2; As[lk + 3][lr] = a3;
        Bs[lk + 0][lr] = w0; Bs[lk + 1][lr] = w1;
        Bs[lk + 2][lr] = w2; Bs[lk + 3][lr] = w3;
        __syncthreads();
#pragma unroll
        for (int k = 0; k < 16; ++k) {
            float4 a4 = *(const float4*)&As[k][ty * 4];
            float4 b4 = *(const float4*)&Bs[k][tx * 4];
            float a[4] = {a4.x, a4.y, a4.z, a4.w};
            float b[4] = {b4.x, b4.y, b4.z, b4.w};
#pragma unroll
            for (int i = 0; i < 4; ++i)
#pragma unroll
                for (int j = 0; j < 4; ++j)
                    acc[i][j] += a[i] * b[j];
        }
        __syncthreads();
    }

#pragma unroll
    for (int i = 0; i < 4; ++i) {
        int gm = bm + ty * 4 + i;
        if (gm >= M) continue;
#pragma unroll
        for (int j = 0; j < 4; ++j) {
            int gn = bn + tx * 4 + j;
            if (gn >= N) continue;
            float v = acc[i][j];
            if (EPI == EPI_BIAS) v += bias[gn];
            if (EPI == EPI_BIAS_SOFTPLUS) {
                v += bias[gn];
                v = fmaxf(v, 0.f) + log1pf(expf(-fabsf(v)));  // softplus
            }
            size_t off = (size_t)gm * ldc + gn;
            if (C_BF) {
                ((ushortT*)Cv)[off] = f2bf(v);
            } else {
                float* p = (float*)Cv + off;
                *p = (EPI == EPI_ADD) ? v + *p : v;
            }
        }
    }
}

// ----------------------------------------------------------------------------
// RMSNorm: xn[r,:] = x[r,:] * rsqrt(mean(x^2)+1e-5) * w   (768/row, bf16 out)
// ----------------------------------------------------------------------------
__global__ __launch_bounds__(256)
void rmsnorm_kernel(const float* __restrict__ x, const float* __restrict__ w,
                    ushortT* __restrict__ xn)
{
    int r = blockIdx.x;
    const float* xr = x + (size_t)r * DM;
    float v[3];
    float s = 0.f;
#pragma unroll
    for (int i = 0; i < 3; ++i) {
        v[i] = xr[threadIdx.x + i * 256];
        s += v[i] * v[i];
    }
#pragma unroll
    for (int o = 32; o > 0; o >>= 1) s += __shfl_down(s, o, 64);
    __shared__ float wsum[4];
    __shared__ float scale_s;
    int wave = threadIdx.x >> 6;
    if ((threadIdx.x & 63) == 0) wsum[wave] = s;
    __syncthreads();
    if (threadIdx.x == 0) {
        float t = wsum[0] + wsum[1] + wsum[2] + wsum[3];
        scale_s = rsqrtf(t * (1.f / 768.f) + 1e-5f);
    }
    __syncthreads();
    float sc = scale_s;
#pragma unroll
    for (int i = 0; i < 3; ++i) {
        int d = threadIdx.x + i * 256;
        xn[(size_t)r * DM + d] = f2bf(v[i] * sc * w[d]);
    }
}

// ----------------------------------------------------------------------------
// Causal depthwise conv (width 4) + bias + silu.
// ----------------------------------------------------------------------------
__global__ __launch_bounds__(256)
void conv_silu_kernel(const ushortT* __restrict__ xc, const float* __restrict__ cw,
                      const float* __restrict__ cb, ushortT* __restrict__ xin)
{
    int idx = blockIdx.x * 256 + threadIdx.x;
    if (idx >= ROWS * ED) return;
    int e = idx % ED;
    int r = idx / ED;
    int l = r % L_TOK;
    float w0 = cw[e * 4 + 0], w1 = cw[e * 4 + 1];
    float w2 = cw[e * 4 + 2], w3 = cw[e * 4 + 3];
    const ushortT* base = xc + (size_t)r * ED + e;
    float acc = cb[e] + w3 * bf2f(base[0]);
    if (l >= 1) acc += w2 * bf2f(base[-(ptrdiff_t)ED]);
    if (l >= 2) acc += w1 * bf2f(base[-(ptrdiff_t)(2 * ED)]);
    if (l >= 3) acc += w0 * bf2f(base[-(ptrdiff_t)(3 * ED)]);
    xin[(size_t)r * ED + e] = f2bf(acc / (1.f + __expf(-acc)));  // silu
}

// ----------------------------------------------------------------------------
// Chunked selective scan, pass 1: per (b,e,chunk) local end-state + sum_delta.
// ----------------------------------------------------------------------------
__global__ __launch_bounds__(64)
void scan_part1(const ushortT* __restrict__ delta, const ushortT* __restrict__ xin,
                const float* __restrict__ dbc, const float* __restrict__ a_log,
                float* __restrict__ hend, float* __restrict__ sdl)
{
    __shared__ float BsL[CLEN * 16];
    const int tid = threadIdx.x;
    const int bid = blockIdx.x;
    const int eg = bid % EGB;
    const int c  = (bid / EGB) % C_CH;
    const int b  = bid / (EGB * C_CH);
    const int e  = eg * 64 + tid;
    const int l0 = c * CLEN;
    const int rb = b * L_TOK + l0;

    for (int i = tid; i < CLEN * 16; i += 64) {
        int s = i >> 4, n = i & 15;
        BsL[i] = dbc[(size_t)(rb + s) * 80 + 48 + n];
    }
    __syncthreads();

    float a[16];
    const float* ar = a_log + (size_t)e * 16;
#pragma unroll
    for (int n = 0; n < 16; ++n) a[n] = -__expf(ar[n]);

    float h[16];
#pragma unroll
    for (int n = 0; n < 16; ++n) h[n] = 0.f;
    float sum_dl = 0.f;

    const size_t base = (size_t)rb * ED + e;
    float rdl[7], rxi[7];
#pragma unroll
    for (int j = 0; j < 7; ++j) {
        rdl[j] = bf2f(delta[base + (size_t)j * ED]);
        rxi[j] = bf2f(xin[base + (size_t)j * ED]);
    }
    for (int s0 = 0; s0 < CLEN; s0 += 7) {
#pragma unroll
        for (int j = 0; j < 7; ++j) {
            const int s = s0 + j;
            float dl = rdl[j], xi = rxi[j];
            int sp = s + 7; if (sp > CLEN - 1) sp = CLEN - 1;   // clamped prefetch
            rdl[j] = bf2f(delta[base + (size_t)sp * ED]);
            rxi[j] = bf2f(xin[base + (size_t)sp * ED]);
            float dlxi = dl * xi;
            sum_dl += dl;
#pragma unroll
            for (int n = 0; n < 16; ++n)
                h[n] = __expf(dl * a[n]) * h[n] + dlxi * BsL[s * 16 + n];
        }
    }

    float* hp = hend + (((size_t)b * ED + e) * C_CH + c) * 16;
#pragma unroll
    for (int n = 0; n < 16; ++n) hp[n] = h[n];
    sdl[((size_t)b * ED + e) * C_CH + c] = sum_dl;
}

// ----------------------------------------------------------------------------
// Chunked scan, pass 2: combine predecessor summaries, re-run chunk, emit y.
// ----------------------------------------------------------------------------
__global__ __launch_bounds__(64)
void scan_part2(const ushortT* __restrict__ delta, const ushortT* __restrict__ xin,
                const float* __restrict__ dbc, const ushortT* __restrict__ zb,
                const float* __restrict__ a_log, const float* __restrict__ dvec,
                const float* __restrict__ hend, const float* __restrict__ sdl,
                ushortT* __restrict__ y)
{
    __shared__ float BsL[CLEN * 16];
    __shared__ float CsL[CLEN * 16];
    const int tid = threadIdx.x;
    const int bid = blockIdx.x;
    const int eg = bid % EGB;
    const int c  = (bid / EGB) % C_CH;
    const int b  = bid / (EGB * C_CH);
    const int e  = eg * 64 + tid;
    const int l0 = c * CLEN;
    const int rb = b * L_TOK + l0;

    for (int i = tid; i < CLEN * 16; i += 64) {
        int s = i >> 4, n = i & 15;
        size_t row = (size_t)(rb + s) * 80;
        BsL[i] = dbc[row + 48 + n];
        CsL[i] = dbc[row + 64 + n];
    }
    __syncthreads();

    float a[16];
    const float* ar = a_log + (size_t)e * 16;
#pragma unroll
    for (int n = 0; n < 16; ++n) a[n] = -__expf(ar[n]);
    const float dcf = dvec[e];

    float h[16];
#pragma unroll
    for (int n = 0; n < 16; ++n) h[n] = 0.f;
    const float* hb = hend + (((size_t)b * ED + e) * C_CH) * 16;
    const float* sb = sdl + ((size_t)b * ED + e) * C_CH;
    for (int cc = 0; cc < c; ++cc) {
        float sv = sb[cc];
#pragma unroll
        for (int n = 0; n < 16; ++n)
            h[n] = __expf(a[n] * sv) * h[n] + hb[cc * 16 + n];
    }

    const size_t base = (size_t)rb * ED + e;
    float rdl[7], rxi[7], rz[7];
#pragma unroll
    for (int j = 0; j < 7; ++j) {
        rdl[j] = bf2f(delta[base + (size_t)j * ED]);
        rxi[j] = bf2f(xin[base + (size_t)j * ED]);
        rz[j]  = bf2f(zb[base + (size_t)j * ED]);
    }
    for (int s0 = 0; s0 < CLEN; s0 += 7) {
#pragma unroll
        for (int j = 0; j < 7; ++j) {
            const int s = s0 + j;
            float dl = rdl[j], xi = rxi[j], z = rz[j];
            int sp = s + 7; if (sp > CLEN - 1) sp = CLEN - 1;   // clamped prefetch
            rdl[j] = bf2f(delta[base + (size_t)sp * ED]);
            rxi[j] = bf2f(xin[base + (size_t)sp * ED]);
            rz[j]  = bf2f(zb[base + (size_t)sp * ED]);
            float dlxi = dl * xi;
            float yv = 0.f;
#pragma unroll
            for (int n = 0; n < 16; ++n) {
                h[n] = __expf(dl * a[n]) * h[n] + dlxi * BsL[s * 16 + n];
                yv += h[n] * CsL[s * 16 + n];
            }
            yv += dcf * xi;
            float sz = z / (1.f + __expf(-z));
            y[base + (size_t)s * ED] = f2bf(yv * sz);
        }
    }
}

// ----------------------------------------------------------------------------
// im2col for patch embed: P[r, k] (bf16) with r=(b, img, patch), k=(c,ph,pw)
// ----------------------------------------------------------------------------
__global__ __launch_bounds__(256)
void im2col_kernel(const float* __restrict__ rgb, const float* __restrict__ timg,
                   ushortT* __restrict__ P)
{
    int idx = blockIdx.x * 256 + threadIdx.x;
    if (idx >= ROWS * DM) return;
    int k = idx % DM;
    int r = idx / DM;
    int b = r / L_TOK;
    int l = r % L_TOK;
    const float* img = (l < 196) ? rgb : timg;
    int p  = (l < 196) ? l : l - 196;
    int py = p / 14, px = p % 14;
    int c  = k >> 8;
    int ph = (k >> 4) & 15;
    int pw = k & 15;
    P[idx] = f2bf(img[(((size_t)b * 3 + c) * 224 + (py * 16 + ph)) * 224 + (px * 16 + pw)]);
}

// ----------------------------------------------------------------------------
// Output: out[(l*768 + d)*8 + b] = x[b, l, d]
// ----------------------------------------------------------------------------
__global__ __launch_bounds__(256)
void out_transpose_kernel(const float* __restrict__ x, float* __restrict__ out)
{
    int idx = blockIdx.x * 256 + threadIdx.x;
    if (idx >= ROWS * DM) return;
    int b = idx & 7;
    int d = (idx >> 3) % DM;
    int l = idx / (8 * DM);
    out[idx] = x[((size_t)(b * L_TOK + l)) * DM + d];
}

// ----------------------------------------------------------------------------
extern "C" void kernel_launch(void* const* d_in, const int* in_sizes, int n_in,
                              void* d_out, int out_size, void* d_ws, size_t ws_size,
                              hipStream_t stream)
{
    (void)in_sizes; (void)n_in; (void)out_size; (void)ws_size;

    const float* rgb  = (const float*)d_in[0];
    const float* timg = (const float*)d_in[1];
    const float* pe_w = (const float*)d_in[2];   // [768, 3,16,16] -> [768][768]
    const float* pe_b = (const float*)d_in[3];
    const float* in_w = (const float*)d_in[4];   // [8, 3072, 768]
    const float* cw   = (const float*)d_in[5];   // [8, 1536, 1, 4]
    const float* cb   = (const float*)d_in[6];   // [8, 1536]
    const float* xw   = (const float*)d_in[7];   // [8, 80, 1536]
    const float* dtw  = (const float*)d_in[8];   // [8, 1536, 48]
    const float* dtb  = (const float*)d_in[9];   // [8, 1536]
    const float* alog = (const float*)d_in[10];  // [8, 1536, 16]
    const float* dvec = (const float*)d_in[11];  // [8, 1536]
    const float* ow   = (const float*)d_in[12];  // [8, 768, 1536]
    const float* nw   = (const float*)d_in[13];  // [8, 768]

    char* p = (char*)d_ws;
    float*   X   = (float*)p;    p += (size_t)ROWS * DM * 4;
    ushortT* XC  = (ushortT*)p;  p += (size_t)ROWS * ED * 2;   // conv-in / patches / y
    ushortT* Zb  = (ushortT*)p;  p += (size_t)ROWS * ED * 2;
    ushortT* XIN = (ushortT*)p;  p += (size_t)ROWS * ED * 2;
    ushortT* DEL = (ushortT*)p;  p += (size_t)ROWS * ED * 2;   // delta; front = xn
    float*   DBC = (float*)p;    p += (size_t)ROWS * 80 * 4;
    ushortT* XN  = DEL;          // overlay: xn dead before delta is written

    // chunk-scan scratch lives in d_out (dead until out_transpose):
    float* HEND = (float*)d_out;
    float* SDL  = HEND + (size_t)BATCH * ED * C_CH * 16;

    dim3 b256(256);
    const int MT = (ROWS + 127) / 128;            // 25 M-tiles
    const int SCAN_BLOCKS = BATCH * C_CH * EGB;   // 1536

    // ---- patch embed: im2col (bf16) into XC, then MFMA GEMM+bias -> X ----
    im2col_kernel<<<(ROWS * DM + 255) / 256, b256, 0, stream>>>(rgb, timg, XC);
    gemm_mfma<EPI_BIAS, false, false><<<dim3(DM / 128, MT), b256, 0, stream>>>(
        XC, DM, pe_w, DM, pe_b, X, nullptr, DM, ROWS, DM, DM);

    for (int i = 0; i < 8; ++i) {
        const float* in_wi = in_w + (size_t)i * 2 * ED * DM;
        const float* cwi   = cw   + (size_t)i * ED * 4;
        const float* cbi   = cb   + (size_t)i * ED;
        const float* xwi   = xw   + (size_t)i * 80 * ED;
        const float* dtwi  = dtw  + (size_t)i * ED * DTR;
        const float* dtbi  = dtb  + (size_t)i * ED;
        const float* ali   = alog + (size_t)i * ED * NST;
        const float* dvi   = dvec + (size_t)i * ED;
        const float* owi   = ow   + (size_t)i * DM * ED;
        const float* nwi   = nw   + (size_t)i * DM;

        // xn = rmsnorm(x)  -> XN (bf16, overlaid on DEL)
        rmsnorm_kernel<<<ROWS, b256, 0, stream>>>(X, nwi, XN);
        // [xc | z] = xn @ in_w^T  (single MFMA dispatch, block-uniform split)
        gemm_mfma<EPI_STORE, true, true><<<dim3(2 * ED / 128, MT), b256, 0, stream>>>(
            XN, DM, in_wi, DM, nullptr, XC, Zb, ED, ROWS, 2 * ED, DM);
        // xin = silu(causal_conv(xc) + cb)
        conv_silu_kernel<<<(ROWS * ED + 255) / 256, b256, 0, stream>>>(
            XC, cwi, cbi, XIN);
        // dbc = xin @ xw^T  -> DBC fp32 (zero + split-K atomic accumulate)
        hipMemsetAsync(DBC, 0, (size_t)ROWS * 80 * 4, stream);
        gemm_nt_splitk<<<dim3(2, ROWS / 64, 8), b256, 0, stream>>>(
            XIN, ED, xwi, ED, DBC, 80, ROWS, 80, ED, ED / 8);
        // delta = softplus(dbc[:, :48] @ dtw^T + dtb) -> DEL bf16   (VALU: K=48)
        gemm_nt<EPI_BIAS_SOFTPLUS, false, true><<<dim3(ED / 64, ROWS / 64), b256, 0, stream>>>(
            DBC, 80, dtwi, DTR, dtbi, DEL, ED, ROWS, ED, DTR);
        // chunked scan: pass1 summaries -> pass2 seeded scan + y  -> XC
        scan_part1<<<SCAN_BLOCKS, 64, 0, stream>>>(
            DEL, XIN, DBC, ali, HEND, SDL);
        scan_part2<<<SCAN_BLOCKS, 64, 0, stream>>>(
            DEL, XIN, DBC, Zb, ali, dvi, HEND, SDL, XC);
        // x += y @ ow^T   (MFMA)
        gemm_mfma<EPI_ADD, false, false><<<dim3(DM / 128, MT), b256, 0, stream>>>(
            XC, ED, owi, ED, nullptr, X, nullptr, DM, ROWS, DM, ED);
    }

    out_transpose_kernel<<<(ROWS * DM + 255) / 256, b256, 0, stream>>>(
        X, (float*)d_out);
}

// Round 7
// 2060.986 us; speedup vs baseline: 2.1843x; 1.0803x over previous
//
#include <hip/hip_runtime.h>
#include <cstddef>
#include <cstdint>

// ---- model dims ----
#define L_TOK 392
#define BATCH 8
#define DM    768
#define ED    1536
#define NST   16
#define DTR   48
#define ROWS  (BATCH * L_TOK)   // 3136

// chunked scan
#define C_CH 8
#define CLEN 49                 // L_TOK / C_CH
#define EGB  24                 // ED/64 e-groups

// Workspace ~47 MB (round-1 overran at 107MB and corrupted pristine inputs --
// do NOT grow d_ws). Chunk-scan scratch lives in d_out (dead until transpose).

typedef unsigned short ushortT;
typedef __bf16 bf16x8 __attribute__((ext_vector_type(8)));
typedef unsigned short us8 __attribute__((ext_vector_type(8)));
typedef unsigned short us4 __attribute__((ext_vector_type(4)));
typedef float f32x4 __attribute__((ext_vector_type(4)));

__device__ __forceinline__ float bf2f(ushortT u) {
    union { unsigned int i; float f; } v; v.i = ((unsigned int)u) << 16; return v.f;
}
__device__ __forceinline__ ushortT f2bf(float f) {
    union { float f; unsigned int i; } v; v.f = f;
    unsigned int r = v.i + 0x7FFFu + ((v.i >> 16) & 1u);   // round-nearest-even
    return (ushortT)(r >> 16);
}

enum { EPI_STORE = 0, EPI_BIAS = 1, EPI_BIAS_SOFTPLUS = 2, EPI_ADD = 3 };

// ----------------------------------------------------------------------------
// Pipelined MFMA GEMM: C[M,N] (epi)= A[M,K](bf16) @ W[N,K](fp32)^T
// 128x128 tile, BK=32, 256 thr = 4 waves (2x2), 4x4 mfma_f32_16x16x32_bf16.
// Round-6 fix: register-prefetch + LDS double-buffer (was single-buffered ->
// every BK-iter ate full HBM latency serially; MfmaUtil 4%, all pipes idle).
// Loop body: issue next tile's global loads -> MFMA on LDS[cur] -> write
// prefetched regs to LDS[cur^1] -> one barrier.
// SPLITK: blockIdx.z covers K-chunk; epilogue atomicAdd (fp32 C only).
// SPLIT: block-uniform output split at column ED (in_proj -> XC | Zb).
// ----------------------------------------------------------------------------
template <int EPI, bool C_BF, bool SPLIT, bool ATOMIC>
__global__ __launch_bounds__(256)
void gemm_mfma(const ushortT* __restrict__ A, int lda,
               const float* __restrict__ W, int ldw,
               const float* __restrict__ bias,
               void* __restrict__ Cv, void* __restrict__ Cv2, int ldc,
               int M, int N, int K, int kchunk)
{
    __shared__ ushortT As[2][128 * 40];
    __shared__ ushortT Ws[2][128 * 40];

    const int tid  = threadIdx.x;
    const int lane = tid & 63;
    const int wave = tid >> 6;
    const int wm   = wave >> 1;        // 0..1
    const int wn   = wave & 1;         // 0..1
    const int quad = lane >> 4;        // 0..3
    const int l16  = lane & 15;        // 0..15

    const int m0 = blockIdx.y * 128;
    const int n0 = blockIdx.x * 128;
    const int kb = blockIdx.z * kchunk;
    const int KT = kchunk / 32;

    const int ar    = tid >> 1;        // 0..127  A row
    const int ahalf = tid & 1;         // 16-elem half
    const int wr    = tid >> 3;        // 0..31   W row (x4 iters)
    const int wc    = (tid & 7) * 4;   // float4 col

    const int gm_a = m0 + ar;
    const ushortT* aptr = A + (size_t)gm_a * lda + ahalf * 16;

    us8 a0r = {0,0,0,0,0,0,0,0}, a1r = {0,0,0,0,0,0,0,0};
    float4 wfr[4];

    auto g_load = [&](int k0) {
        if (gm_a < M) {
            const ushortT* src = aptr + k0;
            a0r = *(const us8*)(src);
            a1r = *(const us8*)(src + 8);
        }
#pragma unroll
        for (int it = 0; it < 4; ++it) {
            int row = it * 32 + wr;
            wfr[it] = *(const float4*)(W + (size_t)(n0 + row) * ldw + k0 + wc);
        }
    };
    auto l_store = [&](int buf) {
        *(us8*)&As[buf][ar * 40 + ahalf * 16]     = a0r;
        *(us8*)&As[buf][ar * 40 + ahalf * 16 + 8] = a1r;
#pragma unroll
        for (int it = 0; it < 4; ++it) {
            int row = it * 32 + wr;
            float4 f = wfr[it];
            us4 h; h.x = f2bf(f.x); h.y = f2bf(f.y); h.z = f2bf(f.z); h.w = f2bf(f.w);
            *(us4*)&Ws[buf][row * 40 + wc] = h;
        }
    };

    f32x4 acc[4][4] = {};

    g_load(kb);
    l_store(0);
    __syncthreads();

    for (int kt = 0; kt < KT; ++kt) {
        const int cur = kt & 1;
        if (kt + 1 < KT) g_load(kb + (kt + 1) * 32);   // overlap with compute

        bf16x8 af[4], bw[4];
#pragma unroll
        for (int t = 0; t < 4; ++t) {
            us8 ta = *(const us8*)&As[cur][(wm * 64 + t * 16 + l16) * 40 + quad * 8];
            af[t] = __builtin_bit_cast(bf16x8, ta);
            us8 tb = *(const us8*)&Ws[cur][(wn * 64 + t * 16 + l16) * 40 + quad * 8];
            bw[t] = __builtin_bit_cast(bf16x8, tb);
        }
#pragma unroll
        for (int i = 0; i < 4; ++i)
#pragma unroll
            for (int j = 0; j < 4; ++j)
                acc[i][j] = __builtin_amdgcn_mfma_f32_16x16x32_bf16(
                    af[i], bw[j], acc[i][j], 0, 0, 0);

        if (kt + 1 < KT) l_store(cur ^ 1);   // waits vmcnt here, after MFMAs
        __syncthreads();
    }

#pragma unroll
    for (int i = 0; i < 4; ++i) {
#pragma unroll
        for (int r = 0; r < 4; ++r) {
            int gm = m0 + wm * 64 + i * 16 + quad * 4 + r;
            if (gm >= M) continue;
#pragma unroll
            for (int j = 0; j < 4; ++j) {
                int gn = n0 + wn * 64 + j * 16 + l16;
                float v = acc[i][j][r];
                if (EPI == EPI_BIAS) v += bias[gn];
                void* dst = Cv;
                int cn = gn;
                if (SPLIT && gn >= ED) { dst = Cv2; cn = gn - ED; }  // block-uniform
                size_t off = (size_t)gm * ldc + cn;
                if (ATOMIC) {
                    atomicAdd((float*)dst + off, v);
                } else if (C_BF) {
                    ((ushortT*)dst)[off] = f2bf(v);
                } else {
                    float* p = (float*)dst + off;
                    *p = (EPI == EPI_ADD) ? v + *p : v;
                }
            }
        }
    }
}

// ----------------------------------------------------------------------------
// Split-K VALU GEMM for x_proj (N=80): fp32 atomicAdd epilogue (C pre-zeroed).
// ----------------------------------------------------------------------------
__global__ __launch_bounds__(256)
void gemm_nt_splitk(const ushortT* __restrict__ A, int lda,
                    const float* __restrict__ W, int ldw,
                    float* __restrict__ C, int ldc,
                    int M, int N, int K, int kchunk)
{
    __shared__ float As[16][68];
    __shared__ float Bs[16][68];
    const int tid = threadIdx.x;
    const int tx  = tid & 15;
    const int ty  = tid >> 4;
    const int bm  = blockIdx.y * 64;
    const int bn  = blockIdx.x * 64;
    const int lr  = tid >> 2;
    const int lk  = (tid & 3) * 4;
    const int kb  = blockIdx.z * kchunk;
    const int ke  = kb + kchunk;

    float acc[4][4] = {};

    for (int k0 = kb; k0 < ke; k0 += 16) {
        float a0 = 0.f, a1 = 0.f, a2 = 0.f, a3 = 0.f;
        float w0 = 0.f, w1 = 0.f, w2 = 0.f, w3 = 0.f;
        int ga = bm + lr;
        if (ga < M) {
            ushort4 t = *(const ushort4*)(A + (size_t)ga * lda + k0 + lk);
            a0 = bf2f(t.x); a1 = bf2f(t.y); a2 = bf2f(t.z); a3 = bf2f(t.w);
        }
        int gw = bn + lr;
        if (gw < N) {
            float4 t = *(const float4*)(W + (size_t)gw * ldw + k0 + lk);
            w0 = t.x; w1 = t.y; w2 = t.z; w3 = t.w;
        }
        As[lk + 0][lr] = a0; As[lk + 1][lr] = a1;
        As[lk + 2][lr] = a2; As[lk + 3][lr] = a3;
        Bs[lk + 0][lr] = w0; Bs[lk + 1][lr] = w1;
        Bs[lk + 2][lr] = w2; Bs[lk + 3][lr] = w3;
        __syncthreads();
#pragma unroll
        for (int k = 0; k < 16; ++k) {
            float4 a4 = *(const float4*)&As[k][ty * 4];
            float4 b4 = *(const float4*)&Bs[k][tx * 4];
            float a[4] = {a4.x, a4.y, a4.z, a4.w};
            float b[4] = {b4.x, b4.y, b4.z, b4.w};
#pragma unroll
            for (int i = 0; i < 4; ++i)
#pragma unroll
                for (int j = 0; j < 4; ++j)
                    acc[i][j] += a[i] * b[j];
        }
        __syncthreads();
    }

#pragma unroll
    for (int i = 0; i < 4; ++i) {
        int gm = bm + ty * 4 + i;
        if (gm >= M) continue;
#pragma unroll
        for (int j = 0; j < 4; ++j) {
            int gn = bn + tx * 4 + j;
            if (gn >= N) continue;
            atomicAdd(C + (size_t)gm * ldc + gn, acc[i][j]);
        }
    }
}

// ----------------------------------------------------------------------------
// VALU tiled GEMM (dt_proj: K=48).
// ----------------------------------------------------------------------------
template <int EPI, bool A_BF, bool C_BF>
__global__ __launch_bounds__(256)
void gemm_nt(const void* __restrict__ Av, int lda,
             const float* __restrict__ W, int ldw,
             const float* __restrict__ bias,
             void* __restrict__ Cv, int ldc,
             int M, int N, int K)
{
    __shared__ float As[16][68];
    __shared__ float Bs[16][68];
    const int tid = threadIdx.x;
    const int tx  = tid & 15;
    const int ty  = tid >> 4;
    const int bm  = blockIdx.y * 64;
    const int bn  = blockIdx.x * 64;
    const int lr  = tid >> 2;
    const int lk  = (tid & 3) * 4;

    float acc[4][4] = {};

    for (int k0 = 0; k0 < K; k0 += 16) {
        float a0 = 0.f, a1 = 0.f, a2 = 0.f, a3 = 0.f;
        float w0 = 0.f, w1 = 0.f, w2 = 0.f, w3 = 0.f;
        int ga = bm + lr;
        if (ga < M) {
            if (A_BF) {
                const ushortT* A = (const ushortT*)Av;
                ushort4 t = *(const ushort4*)(A + (size_t)ga * lda + k0 + lk);
                a0 = bf2f(t.x); a1 = bf2f(t.y); a2 = bf2f(t.z); a3 = bf2f(t.w);
            } else {
                const float* A = (const float*)Av;
                float4 t = *(const float4*)(A + (size_t)ga * lda + k0 + lk);
                a0 = t.x; a1 = t.y; a2 = t.z; a3 = t.w;
            }
        }
        int gw = bn + lr;
        if (gw < N) {
            float4 t = *(const float4*)(W + (size_t)gw * ldw + k0 + lk);
            w0 = t.x; w1 = t.y; w2 = t.z; w3 = t.w;
        }
        As[lk + 0][lr] = a0; As[lk + 1][lr] = a1;
        As[lk + 2][lr] = a2; As[lk + 3][lr] = a3;
        Bs[lk + 0][lr] = w0; Bs[lk + 1][lr] = w1;
        Bs[lk + 2][lr] = w2; Bs[lk + 3][lr] = w3;
        __syncthreads();
#pragma unroll
        for (int k = 0; k < 16; ++k) {
            float4 a4 = *(const float4*)&As[k][ty * 4];
            float4 b4 = *(const float4*)&Bs[k][tx * 4];
            float a[4] = {a4.x, a4.y, a4.z, a4.w};
            float b[4] = {b4.x, b4.y, b4.z, b4.w};
#pragma unroll
            for (int i = 0; i < 4; ++i)
#pragma unroll
                for (int j = 0; j < 4; ++j)
                    acc[i][j] += a[i] * b[j];
        }
        __syncthreads();
    }

#pragma unroll
    for (int i = 0; i < 4; ++i) {
        int gm = bm + ty * 4 + i;
        if (gm >= M) continue;
#pragma unroll
        for (int j = 0; j < 4; ++j) {
            int gn = bn + tx * 4 + j;
            if (gn >= N) continue;
            float v = acc[i][j];
            if (EPI == EPI_BIAS) v += bias[gn];
            if (EPI == EPI_BIAS_SOFTPLUS) {
                v += bias[gn];
                v = fmaxf(v, 0.f) + log1pf(expf(-fabsf(v)));  // softplus
            }
            size_t off = (size_t)gm * ldc + gn;
            if (C_BF) {
                ((ushortT*)Cv)[off] = f2bf(v);
            } else {
                float* p = (float*)Cv + off;
                *p = (EPI == EPI_ADD) ? v + *p : v;
            }
        }
    }
}

// ----------------------------------------------------------------------------
// RMSNorm: xn[r,:] = x[r,:] * rsqrt(mean(x^2)+1e-5) * w   (768/row, bf16 out)
// ----------------------------------------------------------------------------
__global__ __launch_bounds__(256)
void rmsnorm_kernel(const float* __restrict__ x, const float* __restrict__ w,
                    ushortT* __restrict__ xn)
{
    int r = blockIdx.x;
    const float* xr = x + (size_t)r * DM;
    float v[3];
    float s = 0.f;
#pragma unroll
    for (int i = 0; i < 3; ++i) {
        v[i] = xr[threadIdx.x + i * 256];
        s += v[i] * v[i];
    }
#pragma unroll
    for (int o = 32; o > 0; o >>= 1) s += __shfl_down(s, o, 64);
    __shared__ float wsum[4];
    __shared__ float scale_s;
    int wave = threadIdx.x >> 6;
    if ((threadIdx.x & 63) == 0) wsum[wave] = s;
    __syncthreads();
    if (threadIdx.x == 0) {
        float t = wsum[0] + wsum[1] + wsum[2] + wsum[3];
        scale_s = rsqrtf(t * (1.f / 768.f) + 1e-5f);
    }
    __syncthreads();
    float sc = scale_s;
#pragma unroll
    for (int i = 0; i < 3; ++i) {
        int d = threadIdx.x + i * 256;
        xn[(size_t)r * DM + d] = f2bf(v[i] * sc * w[d]);
    }
}

// ----------------------------------------------------------------------------
// Causal depthwise conv (width 4) + bias + silu.
// ----------------------------------------------------------------------------
__global__ __launch_bounds__(256)
void conv_silu_kernel(const ushortT* __restrict__ xc, const float* __restrict__ cw,
                      const float* __restrict__ cb, ushortT* __restrict__ xin)
{
    int idx = blockIdx.x * 256 + threadIdx.x;
    if (idx >= ROWS * ED) return;
    int e = idx % ED;
    int r = idx / ED;
    int l = r % L_TOK;
    float w0 = cw[e * 4 + 0], w1 = cw[e * 4 + 1];
    float w2 = cw[e * 4 + 2], w3 = cw[e * 4 + 3];
    const ushortT* base = xc + (size_t)r * ED + e;
    float acc = cb[e] + w3 * bf2f(base[0]);
    if (l >= 1) acc += w2 * bf2f(base[-(ptrdiff_t)ED]);
    if (l >= 2) acc += w1 * bf2f(base[-(ptrdiff_t)(2 * ED)]);
    if (l >= 3) acc += w0 * bf2f(base[-(ptrdiff_t)(3 * ED)]);
    xin[(size_t)r * ED + e] = f2bf(acc / (1.f + __expf(-acc)));  // silu
}

// ----------------------------------------------------------------------------
// Chunked selective scan, pass 1: per (b,e,chunk) local end-state + sum_delta.
// ----------------------------------------------------------------------------
__global__ __launch_bounds__(64)
void scan_part1(const ushortT* __restrict__ delta, const ushortT* __restrict__ xin,
                const float* __restrict__ dbc, const float* __restrict__ a_log,
                float* __restrict__ hend, float* __restrict__ sdl)
{
    __shared__ float BsL[CLEN * 16];
    const int tid = threadIdx.x;
    const int bid = blockIdx.x;
    const int eg = bid % EGB;
    const int c  = (bid / EGB) % C_CH;
    const int b  = bid / (EGB * C_CH);
    const int e  = eg * 64 + tid;
    const int l0 = c * CLEN;
    const int rb = b * L_TOK + l0;

    for (int i = tid; i < CLEN * 16; i += 64) {
        int s = i >> 4, n = i & 15;
        BsL[i] = dbc[(size_t)(rb + s) * 80 + 48 + n];
    }
    __syncthreads();

    float a[16];
    const float* ar = a_log + (size_t)e * 16;
#pragma unroll
    for (int n = 0; n < 16; ++n) a[n] = -__expf(ar[n]);

    float h[16];
#pragma unroll
    for (int n = 0; n < 16; ++n) h[n] = 0.f;
    float sum_dl = 0.f;

    const size_t base = (size_t)rb * ED + e;
    float rdl[7], rxi[7];
#pragma unroll
    for (int j = 0; j < 7; ++j) {
        rdl[j] = bf2f(delta[base + (size_t)j * ED]);
        rxi[j] = bf2f(xin[base + (size_t)j * ED]);
    }
    for (int s0 = 0; s0 < CLEN; s0 += 7) {
#pragma unroll
        for (int j = 0; j < 7; ++j) {
            const int s = s0 + j;
            float dl = rdl[j], xi = rxi[j];
            int sp = s + 7; if (sp > CLEN - 1) sp = CLEN - 1;   // clamped prefetch
            rdl[j] = bf2f(delta[base + (size_t)sp * ED]);
            rxi[j] = bf2f(xin[base + (size_t)sp * ED]);
            float dlxi = dl * xi;
            sum_dl += dl;
#pragma unroll
            for (int n = 0; n < 16; ++n)
                h[n] = __expf(dl * a[n]) * h[n] + dlxi * BsL[s * 16 + n];
        }
    }

    float* hp = hend + (((size_t)b * ED + e) * C_CH + c) * 16;
#pragma unroll
    for (int n = 0; n < 16; ++n) hp[n] = h[n];
    sdl[((size_t)b * ED + e) * C_CH + c] = sum_dl;
}

// ----------------------------------------------------------------------------
// Chunked scan, pass 2: combine predecessor summaries, re-run chunk, emit y.
// ----------------------------------------------------------------------------
__global__ __launch_bounds__(64)
void scan_part2(const ushortT* __restrict__ delta, const ushortT* __restrict__ xin,
                const float* __restrict__ dbc, const ushortT* __restrict__ zb,
                const float* __restrict__ a_log, const float* __restrict__ dvec,
                const float* __restrict__ hend, const float* __restrict__ sdl,
                ushortT* __restrict__ y)
{
    __shared__ float BsL[CLEN * 16];
    __shared__ float CsL[CLEN * 16];
    const int tid = threadIdx.x;
    const int bid = blockIdx.x;
    const int eg = bid % EGB;
    const int c  = (bid / EGB) % C_CH;
    const int b  = bid / (EGB * C_CH);
    const int e  = eg * 64 + tid;
    const int l0 = c * CLEN;
    const int rb = b * L_TOK + l0;

    for (int i = tid; i < CLEN * 16; i += 64) {
        int s = i >> 4, n = i & 15;
        size_t row = (size_t)(rb + s) * 80;
        BsL[i] = dbc[row + 48 + n];
        CsL[i] = dbc[row + 64 + n];
    }
    __syncthreads();

    float a[16];
    const float* ar = a_log + (size_t)e * 16;
#pragma unroll
    for (int n = 0; n < 16; ++n) a[n] = -__expf(ar[n]);
    const float dcf = dvec[e];

    float h[16];
#pragma unroll
    for (int n = 0; n < 16; ++n) h[n] = 0.f;
    const float* hb = hend + (((size_t)b * ED + e) * C_CH) * 16;
    const float* sb = sdl + ((size_t)b * ED + e) * C_CH;
    for (int cc = 0; cc < c; ++cc) {
        float sv = sb[cc];
#pragma unroll
        for (int n = 0; n < 16; ++n)
            h[n] = __expf(a[n] * sv) * h[n] + hb[cc * 16 + n];
    }

    const size_t base = (size_t)rb * ED + e;
    float rdl[7], rxi[7], rz[7];
#pragma unroll
    for (int j = 0; j < 7; ++j) {
        rdl[j] = bf2f(delta[base + (size_t)j * ED]);
        rxi[j] = bf2f(xin[base + (size_t)j * ED]);
        rz[j]  = bf2f(zb[base + (size_t)j * ED]);
    }
    for (int s0 = 0; s0 < CLEN; s0 += 7) {
#pragma unroll
        for (int j = 0; j < 7; ++j) {
            const int s = s0 + j;
            float dl = rdl[j], xi = rxi[j], z = rz[j];
            int sp = s + 7; if (sp > CLEN - 1) sp = CLEN - 1;   // clamped prefetch
            rdl[j] = bf2f(delta[base + (size_t)sp * ED]);
            rxi[j] = bf2f(xin[base + (size_t)sp * ED]);
            rz[j]  = bf2f(zb[base + (size_t)sp * ED]);
            float dlxi = dl * xi;
            float yv = 0.f;
#pragma unroll
            for (int n = 0; n < 16; ++n) {
                h[n] = __expf(dl * a[n]) * h[n] + dlxi * BsL[s * 16 + n];
                yv += h[n] * CsL[s * 16 + n];
            }
            yv += dcf * xi;
            float sz = z / (1.f + __expf(-z));
            y[base + (size_t)s * ED] = f2bf(yv * sz);
        }
    }
}

// ----------------------------------------------------------------------------
// im2col for patch embed: P[r, k] (bf16) with r=(b, img, patch), k=(c,ph,pw)
// ----------------------------------------------------------------------------
__global__ __launch_bounds__(256)
void im2col_kernel(const float* __restrict__ rgb, const float* __restrict__ timg,
                   ushortT* __restrict__ P)
{
    int idx = blockIdx.x * 256 + threadIdx.x;
    if (idx >= ROWS * DM) return;
    int k = idx % DM;
    int r = idx / DM;
    int b = r / L_TOK;
    int l = r % L_TOK;
    const float* img = (l < 196) ? rgb : timg;
    int p  = (l < 196) ? l : l - 196;
    int py = p / 14, px = p % 14;
    int c  = k >> 8;
    int ph = (k >> 4) & 15;
    int pw = k & 15;
    P[idx] = f2bf(img[(((size_t)b * 3 + c) * 224 + (py * 16 + ph)) * 224 + (px * 16 + pw)]);
}

// ----------------------------------------------------------------------------
// Output: out[(l*768 + d)*8 + b] = x[b, l, d]
// ----------------------------------------------------------------------------
__global__ __launch_bounds__(256)
void out_transpose_kernel(const float* __restrict__ x, float* __restrict__ out)
{
    int idx = blockIdx.x * 256 + threadIdx.x;
    if (idx >= ROWS * DM) return;
    int b = idx & 7;
    int d = (idx >> 3) % DM;
    int l = idx / (8 * DM);
    out[idx] = x[((size_t)(b * L_TOK + l)) * DM + d];
}

// ----------------------------------------------------------------------------
extern "C" void kernel_launch(void* const* d_in, const int* in_sizes, int n_in,
                              void* d_out, int out_size, void* d_ws, size_t ws_size,
                              hipStream_t stream)
{
    (void)in_sizes; (void)n_in; (void)out_size; (void)ws_size;

    const float* rgb  = (const float*)d_in[0];
    const float* timg = (const float*)d_in[1];
    const float* pe_w = (const float*)d_in[2];   // [768, 3,16,16] -> [768][768]
    const float* pe_b = (const float*)d_in[3];
    const float* in_w = (const float*)d_in[4];   // [8, 3072, 768]
    const float* cw   = (const float*)d_in[5];   // [8, 1536, 1, 4]
    const float* cb   = (const float*)d_in[6];   // [8, 1536]
    const float* xw   = (const float*)d_in[7];   // [8, 80, 1536]
    const float* dtw  = (const float*)d_in[8];   // [8, 1536, 48]
    const float* dtb  = (const float*)d_in[9];   // [8, 1536]
    const float* alog = (const float*)d_in[10];  // [8, 1536, 16]
    const float* dvec = (const float*)d_in[11];  // [8, 1536]
    const float* ow   = (const float*)d_in[12];  // [8, 768, 1536]
    const float* nw   = (const float*)d_in[13];  // [8, 768]

    char* p = (char*)d_ws;
    float*   X   = (float*)p;    p += (size_t)ROWS * DM * 4;
    ushortT* XC  = (ushortT*)p;  p += (size_t)ROWS * ED * 2;   // conv-in / patches / y
    ushortT* Zb  = (ushortT*)p;  p += (size_t)ROWS * ED * 2;
    ushortT* XIN = (ushortT*)p;  p += (size_t)ROWS * ED * 2;
    ushortT* DEL = (ushortT*)p;  p += (size_t)ROWS * ED * 2;   // delta; front = xn
    float*   DBC = (float*)p;    p += (size_t)ROWS * 80 * 4;
    ushortT* XN  = DEL;          // overlay: xn dead before delta is written

    // chunk-scan scratch lives in d_out (dead until out_transpose):
    float* HEND = (float*)d_out;
    float* SDL  = HEND + (size_t)BATCH * ED * C_CH * 16;

    dim3 b256(256);
    const int MT = (ROWS + 127) / 128;            // 25 M-tiles
    const int SCAN_BLOCKS = BATCH * C_CH * EGB;   // 1536

    // ---- patch embed: im2col (bf16) into XC, then MFMA GEMM+bias -> X ----
    im2col_kernel<<<(ROWS * DM + 255) / 256, b256, 0, stream>>>(rgb, timg, XC);
    gemm_mfma<EPI_BIAS, false, false, false><<<dim3(DM / 128, MT), b256, 0, stream>>>(
        XC, DM, pe_w, DM, pe_b, X, nullptr, DM, ROWS, DM, DM, DM);

    for (int i = 0; i < 8; ++i) {
        const float* in_wi = in_w + (size_t)i * 2 * ED * DM;
        const float* cwi   = cw   + (size_t)i * ED * 4;
        const float* cbi   = cb   + (size_t)i * ED;
        const float* xwi   = xw   + (size_t)i * 80 * ED;
        const float* dtwi  = dtw  + (size_t)i * ED * DTR;
        const float* dtbi  = dtb  + (size_t)i * ED;
        const float* ali   = alog + (size_t)i * ED * NST;
        const float* dvi   = dvec + (size_t)i * ED;
        const float* owi   = ow   + (size_t)i * DM * ED;
        const float* nwi   = nw   + (size_t)i * DM;

        // xn = rmsnorm(x)  -> XN (bf16, overlaid on DEL)
        rmsnorm_kernel<<<ROWS, b256, 0, stream>>>(X, nwi, XN);
        // [xc | z] = xn @ in_w^T  (single MFMA dispatch, block-uniform split)
        gemm_mfma<EPI_STORE, true, true, false><<<dim3(2 * ED / 128, MT), b256, 0, stream>>>(
            XN, DM, in_wi, DM, nullptr, XC, Zb, ED, ROWS, 2 * ED, DM, DM);
        // xin = silu(causal_conv(xc) + cb)
        conv_silu_kernel<<<(ROWS * ED + 255) / 256, b256, 0, stream>>>(
            XC, cwi, cbi, XIN);
        // dbc = xin @ xw^T  -> DBC fp32 (zero + split-K atomic accumulate)
        hipMemsetAsync(DBC, 0, (size_t)ROWS * 80 * 4, stream);
        gemm_nt_splitk<<<dim3(2, ROWS / 64, 8), b256, 0, stream>>>(
            XIN, ED, xwi, ED, DBC, 80, ROWS, 80, ED, ED / 8);
        // delta = softplus(dbc[:, :48] @ dtw^T + dtb) -> DEL bf16   (VALU: K=48)
        gemm_nt<EPI_BIAS_SOFTPLUS, false, true><<<dim3(ED / 64, ROWS / 64), b256, 0, stream>>>(
            DBC, 80, dtwi, DTR, dtbi, DEL, ED, ROWS, ED, DTR);
        // chunked scan: pass1 summaries -> pass2 seeded scan + y  -> XC
        scan_part1<<<SCAN_BLOCKS, 64, 0, stream>>>(
            DEL, XIN, DBC, ali, HEND, SDL);
        scan_part2<<<SCAN_BLOCKS, 64, 0, stream>>>(
            DEL, XIN, DBC, Zb, ali, dvi, HEND, SDL, XC);
        // x += y @ ow^T   (MFMA, split-K z=2, atomic fp32 accumulate into X)
        gemm_mfma<EPI_ADD, false, false, true><<<dim3(DM / 128, MT, 2), b256, 0, stream>>>(
            XC, ED, owi, ED, nullptr, X, nullptr, DM, ROWS, DM, ED, ED / 2);
    }

    out_transpose_kernel<<<(ROWS * DM + 255) / 256, b256, 0, stream>>>(
        X, (float*)d_out);
}

// Round 8
// 1885.222 us; speedup vs baseline: 2.3880x; 1.0932x over previous
//
#include <hip/hip_runtime.h>
#include <cstddef>
#include <cstdint>

// ---- model dims ----
#define L_TOK 392
#define BATCH 8
#define DM    768
#define ED    1536
#define NST   16
#define DTR   48
#define ROWS  (BATCH * L_TOK)   // 3136

// chunked scan
#define C_CH 8
#define CLEN 49                 // L_TOK / C_CH
#define EGB  24                 // ED/64 e-groups

// x_proj split-K
#define XP_Z  8

// Workspace ~47 MB (round-1 overran at 107MB and corrupted pristine inputs --
// do NOT grow d_ws). Scratch with disjoint lifetimes (x_proj partials POUT,
// scan summaries HEND/SDL) lives in d_out, dead until out_transpose.

typedef unsigned short ushortT;
typedef __bf16 bf16x8 __attribute__((ext_vector_type(8)));
typedef unsigned short us8 __attribute__((ext_vector_type(8)));
typedef unsigned short us4 __attribute__((ext_vector_type(4)));
typedef float f32x4 __attribute__((ext_vector_type(4)));

__device__ __forceinline__ float bf2f(ushortT u) {
    union { unsigned int i; float f; } v; v.i = ((unsigned int)u) << 16; return v.f;
}
__device__ __forceinline__ ushortT f2bf(float f) {
    union { float f; unsigned int i; } v; v.f = f;
    unsigned int r = v.i + 0x7FFFu + ((v.i >> 16) & 1u);   // round-nearest-even
    return (ushortT)(r >> 16);
}

enum { EPI_STORE = 0, EPI_BIAS = 1, EPI_BIAS_SOFTPLUS = 2, EPI_ADD = 3 };

// ----------------------------------------------------------------------------
// Pipelined MFMA GEMM: C[M,N] (epi)= A[M,K](bf16) @ W[N,K](fp32)^T
// 128x128 tile, BK=32, 256 thr = 4 waves (2x2), 4x4 mfma_f32_16x16x32_bf16.
// Register-prefetch + LDS double-buffer (round-6 fix).
// SPLITK: blockIdx.z covers kchunk; ATOMIC: fp32 atomicAdd epilogue;
// PARTIAL: plain fp32 stores to per-z slices (round-7 x_proj: atomics were
// 31MB of HBM write amplification);
// SPLIT: block-uniform output split at column ED (in_proj -> XC | Zb).
// N may be < 128*gridx (x_proj N=80): W staging + epilogue are N-guarded.
// ----------------------------------------------------------------------------
template <int EPI, bool C_BF, bool SPLIT, bool ATOMIC, bool PARTIAL>
__global__ __launch_bounds__(256)
void gemm_mfma(const ushortT* __restrict__ A, int lda,
               const float* __restrict__ W, int ldw,
               const float* __restrict__ bias,
               void* __restrict__ Cv, void* __restrict__ Cv2, int ldc,
               int M, int N, int K, int kchunk)
{
    __shared__ ushortT As[2][128 * 40];
    __shared__ ushortT Ws[2][128 * 40];

    const int tid  = threadIdx.x;
    const int lane = tid & 63;
    const int wave = tid >> 6;
    const int wm   = wave >> 1;        // 0..1
    const int wn   = wave & 1;         // 0..1
    const int quad = lane >> 4;        // 0..3
    const int l16  = lane & 15;        // 0..15

    const int m0 = blockIdx.y * 128;
    const int n0 = blockIdx.x * 128;
    const int kb = blockIdx.z * kchunk;
    const int KT = kchunk / 32;

    const int ar    = tid >> 1;        // 0..127  A row
    const int ahalf = tid & 1;         // 16-elem half
    const int wr    = tid >> 3;        // 0..31   W row (x4 iters)
    const int wc    = (tid & 7) * 4;   // float4 col

    const int gm_a = m0 + ar;
    const ushortT* aptr = A + (size_t)gm_a * lda + ahalf * 16;

    us8 a0r = {0,0,0,0,0,0,0,0}, a1r = {0,0,0,0,0,0,0,0};
    float4 wfr[4];

    auto g_load = [&](int k0) {
        if (gm_a < M) {
            const ushortT* src = aptr + k0;
            a0r = *(const us8*)(src);
            a1r = *(const us8*)(src + 8);
        }
#pragma unroll
        for (int it = 0; it < 4; ++it) {
            int row = it * 32 + wr;
            wfr[it] = (n0 + row < N)
                ? *(const float4*)(W + (size_t)(n0 + row) * ldw + k0 + wc)
                : make_float4(0.f, 0.f, 0.f, 0.f);
        }
    };
    auto l_store = [&](int buf) {
        *(us8*)&As[buf][ar * 40 + ahalf * 16]     = a0r;
        *(us8*)&As[buf][ar * 40 + ahalf * 16 + 8] = a1r;
#pragma unroll
        for (int it = 0; it < 4; ++it) {
            int row = it * 32 + wr;
            float4 f = wfr[it];
            us4 h; h.x = f2bf(f.x); h.y = f2bf(f.y); h.z = f2bf(f.z); h.w = f2bf(f.w);
            *(us4*)&Ws[buf][row * 40 + wc] = h;
        }
    };

    f32x4 acc[4][4] = {};

    g_load(kb);
    l_store(0);
    __syncthreads();

    for (int kt = 0; kt < KT; ++kt) {
        const int cur = kt & 1;
        if (kt + 1 < KT) g_load(kb + (kt + 1) * 32);   // overlap with compute

        bf16x8 af[4], bw[4];
#pragma unroll
        for (int t = 0; t < 4; ++t) {
            us8 ta = *(const us8*)&As[cur][(wm * 64 + t * 16 + l16) * 40 + quad * 8];
            af[t] = __builtin_bit_cast(bf16x8, ta);
            us8 tb = *(const us8*)&Ws[cur][(wn * 64 + t * 16 + l16) * 40 + quad * 8];
            bw[t] = __builtin_bit_cast(bf16x8, tb);
        }
#pragma unroll
        for (int i = 0; i < 4; ++i)
#pragma unroll
            for (int j = 0; j < 4; ++j)
                acc[i][j] = __builtin_amdgcn_mfma_f32_16x16x32_bf16(
                    af[i], bw[j], acc[i][j], 0, 0, 0);

        if (kt + 1 < KT) l_store(cur ^ 1);   // waits vmcnt here, after MFMAs
        __syncthreads();
    }

#pragma unroll
    for (int i = 0; i < 4; ++i) {
#pragma unroll
        for (int r = 0; r < 4; ++r) {
            int gm = m0 + wm * 64 + i * 16 + quad * 4 + r;
            if (gm >= M) continue;
#pragma unroll
            for (int j = 0; j < 4; ++j) {
                int gn = n0 + wn * 64 + j * 16 + l16;
                if (gn >= N) continue;
                float v = acc[i][j][r];
                if (EPI == EPI_BIAS) v += bias[gn];
                void* dst = Cv;
                int cn = gn;
                if (SPLIT && gn >= ED) { dst = Cv2; cn = gn - ED; }  // block-uniform
                size_t off = (size_t)gm * ldc + cn;
                if (PARTIAL) {
                    ((float*)dst)[(size_t)blockIdx.z * M * ldc + off] = v;
                } else if (ATOMIC) {
                    atomicAdd((float*)dst + off, v);
                } else if (C_BF) {
                    ((ushortT*)dst)[off] = f2bf(v);
                } else {
                    float* p = (float*)dst + off;
                    *p = (EPI == EPI_ADD) ? v + *p : v;
                }
            }
        }
    }
}

// ----------------------------------------------------------------------------
// Reduce x_proj split-K partials: DBC[idx] = sum_z POUT[z][idx]
// ----------------------------------------------------------------------------
__global__ __launch_bounds__(256)
void reduce_partials_kernel(const float* __restrict__ P, float* __restrict__ dbc)
{
    int idx = blockIdx.x * 256 + threadIdx.x;
    if (idx >= ROWS * 80) return;
    float s = 0.f;
#pragma unroll
    for (int z = 0; z < XP_Z; ++z)
        s += P[(size_t)z * ROWS * 80 + idx];
    dbc[idx] = s;
}

// ----------------------------------------------------------------------------
// VALU tiled GEMM (dt_proj: K=48).
// ----------------------------------------------------------------------------
template <int EPI, bool A_BF, bool C_BF>
__global__ __launch_bounds__(256)
void gemm_nt(const void* __restrict__ Av, int lda,
             const float* __restrict__ W, int ldw,
             const float* __restrict__ bias,
             void* __restrict__ Cv, int ldc,
             int M, int N, int K)
{
    __shared__ float As[16][68];
    __shared__ float Bs[16][68];
    const int tid = threadIdx.x;
    const int tx  = tid & 15;
    const int ty  = tid >> 4;
    const int bm  = blockIdx.y * 64;
    const int bn  = blockIdx.x * 64;
    const int lr  = tid >> 2;
    const int lk  = (tid & 3) * 4;

    float acc[4][4] = {};

    for (int k0 = 0; k0 < K; k0 += 16) {
        float a0 = 0.f, a1 = 0.f, a2 = 0.f, a3 = 0.f;
        float w0 = 0.f, w1 = 0.f, w2 = 0.f, w3 = 0.f;
        int ga = bm + lr;
        if (ga < M) {
            if (A_BF) {
                const ushortT* A = (const ushortT*)Av;
                ushort4 t = *(const ushort4*)(A + (size_t)ga * lda + k0 + lk);
                a0 = bf2f(t.x); a1 = bf2f(t.y); a2 = bf2f(t.z); a3 = bf2f(t.w);
            } else {
                const float* A = (const float*)Av;
                float4 t = *(const float4*)(A + (size_t)ga * lda + k0 + lk);
                a0 = t.x; a1 = t.y; a2 = t.z; a3 = t.w;
            }
        }
        int gw = bn + lr;
        if (gw < N) {
            float4 t = *(const float4*)(W + (size_t)gw * ldw + k0 + lk);
            w0 = t.x; w1 = t.y; w2 = t.z; w3 = t.w;
        }
        As[lk + 0][lr] = a0; As[lk + 1][lr] = a1;
        As[lk + 2][lr] = a2; As[lk + 3][lr] = a3;
        Bs[lk + 0][lr] = w0; Bs[lk + 1][lr] = w1;
        Bs[lk + 2][lr] = w2; Bs[lk + 3][lr] = w3;
        __syncthreads();
#pragma unroll
        for (int k = 0; k < 16; ++k) {
            float4 a4 = *(const float4*)&As[k][ty * 4];
            float4 b4 = *(const float4*)&Bs[k][tx * 4];
            float a[4] = {a4.x, a4.y, a4.z, a4.w};
            float b[4] = {b4.x, b4.y, b4.z, b4.w};
#pragma unroll
            for (int i = 0; i < 4; ++i)
#pragma unroll
                for (int j = 0; j < 4; ++j)
                    acc[i][j] += a[i] * b[j];
        }
        __syncthreads();
    }

#pragma unroll
    for (int i = 0; i < 4; ++i) {
        int gm = bm + ty * 4 + i;
        if (gm >= M) continue;
#pragma unroll
        for (int j = 0; j < 4; ++j) {
            int gn = bn + tx * 4 + j;
            if (gn >= N) continue;
            float v = acc[i][j];
            if (EPI == EPI_BIAS) v += bias[gn];
            if (EPI == EPI_BIAS_SOFTPLUS) {
                v += bias[gn];
                v = fmaxf(v, 0.f) + log1pf(expf(-fabsf(v)));  // softplus
            }
            size_t off = (size_t)gm * ldc + gn;
            if (C_BF) {
                ((ushortT*)Cv)[off] = f2bf(v);
            } else {
                float* p = (float*)Cv + off;
                *p = (EPI == EPI_ADD) ? v + *p : v;
            }
        }
    }
}

// ----------------------------------------------------------------------------
// RMSNorm: xn[r,:] = x[r,:] * rsqrt(mean(x^2)+1e-5) * w   (768/row, bf16 out)
// ----------------------------------------------------------------------------
__global__ __launch_bounds__(256)
void rmsnorm_kernel(const float* __restrict__ x, const float* __restrict__ w,
                    ushortT* __restrict__ xn)
{
    int r = blockIdx.x;
    const float* xr = x + (size_t)r * DM;
    float v[3];
    float s = 0.f;
#pragma unroll
    for (int i = 0; i < 3; ++i) {
        v[i] = xr[threadIdx.x + i * 256];
        s += v[i] * v[i];
    }
#pragma unroll
    for (int o = 32; o > 0; o >>= 1) s += __shfl_down(s, o, 64);
    __shared__ float wsum[4];
    __shared__ float scale_s;
    int wave = threadIdx.x >> 6;
    if ((threadIdx.x & 63) == 0) wsum[wave] = s;
    __syncthreads();
    if (threadIdx.x == 0) {
        float t = wsum[0] + wsum[1] + wsum[2] + wsum[3];
        scale_s = rsqrtf(t * (1.f / 768.f) + 1e-5f);
    }
    __syncthreads();
    float sc = scale_s;
#pragma unroll
    for (int i = 0; i < 3; ++i) {
        int d = threadIdx.x + i * 256;
        xn[(size_t)r * DM + d] = f2bf(v[i] * sc * w[d]);
    }
}

// ----------------------------------------------------------------------------
// Causal depthwise conv (width 4) + bias + silu.
// ----------------------------------------------------------------------------
__global__ __launch_bounds__(256)
void conv_silu_kernel(const ushortT* __restrict__ xc, const float* __restrict__ cw,
                      const float* __restrict__ cb, ushortT* __restrict__ xin)
{
    int idx = blockIdx.x * 256 + threadIdx.x;
    if (idx >= ROWS * ED) return;
    int e = idx % ED;
    int r = idx / ED;
    int l = r % L_TOK;
    float w0 = cw[e * 4 + 0], w1 = cw[e * 4 + 1];
    float w2 = cw[e * 4 + 2], w3 = cw[e * 4 + 3];
    const ushortT* base = xc + (size_t)r * ED + e;
    float acc = cb[e] + w3 * bf2f(base[0]);
    if (l >= 1) acc += w2 * bf2f(base[-(ptrdiff_t)ED]);
    if (l >= 2) acc += w1 * bf2f(base[-(ptrdiff_t)(2 * ED)]);
    if (l >= 3) acc += w0 * bf2f(base[-(ptrdiff_t)(3 * ED)]);
    xin[(size_t)r * ED + e] = f2bf(acc / (1.f + __expf(-acc)));  // silu
}

// ----------------------------------------------------------------------------
// Chunked selective scan, pass 1: per (b,e,chunk) local end-state + sum_delta.
// ----------------------------------------------------------------------------
__global__ __launch_bounds__(64)
void scan_part1(const ushortT* __restrict__ delta, const ushortT* __restrict__ xin,
                const float* __restrict__ dbc, const float* __restrict__ a_log,
                float* __restrict__ hend, float* __restrict__ sdl)
{
    __shared__ float BsL[CLEN * 16];
    const int tid = threadIdx.x;
    const int bid = blockIdx.x;
    const int eg = bid % EGB;
    const int c  = (bid / EGB) % C_CH;
    const int b  = bid / (EGB * C_CH);
    const int e  = eg * 64 + tid;
    const int l0 = c * CLEN;
    const int rb = b * L_TOK + l0;

    for (int i = tid; i < CLEN * 16; i += 64) {
        int s = i >> 4, n = i & 15;
        BsL[i] = dbc[(size_t)(rb + s) * 80 + 48 + n];
    }
    __syncthreads();

    float a[16];
    const float* ar = a_log + (size_t)e * 16;
#pragma unroll
    for (int n = 0; n < 16; ++n) a[n] = -__expf(ar[n]);

    float h[16];
#pragma unroll
    for (int n = 0; n < 16; ++n) h[n] = 0.f;
    float sum_dl = 0.f;

    const size_t base = (size_t)rb * ED + e;
    float rdl[7], rxi[7];
#pragma unroll
    for (int j = 0; j < 7; ++j) {
        rdl[j] = bf2f(delta[base + (size_t)j * ED]);
        rxi[j] = bf2f(xin[base + (size_t)j * ED]);
    }
    for (int s0 = 0; s0 < CLEN; s0 += 7) {
#pragma unroll
        for (int j = 0; j < 7; ++j) {
            const int s = s0 + j;
            float dl = rdl[j], xi = rxi[j];
            int sp = s + 7; if (sp > CLEN - 1) sp = CLEN - 1;   // clamped prefetch
            rdl[j] = bf2f(delta[base + (size_t)sp * ED]);
            rxi[j] = bf2f(xin[base + (size_t)sp * ED]);
            float dlxi = dl * xi;
            sum_dl += dl;
#pragma unroll
            for (int n = 0; n < 16; ++n)
                h[n] = __expf(dl * a[n]) * h[n] + dlxi * BsL[s * 16 + n];
        }
    }

    float* hp = hend + (((size_t)b * ED + e) * C_CH + c) * 16;
#pragma unroll
    for (int n = 0; n < 16; ++n) hp[n] = h[n];
    sdl[((size_t)b * ED + e) * C_CH + c] = sum_dl;
}

// ----------------------------------------------------------------------------
// Chunked scan, pass 2: combine predecessor summaries, re-run chunk, emit y.
// ----------------------------------------------------------------------------
__global__ __launch_bounds__(64)
void scan_part2(const ushortT* __restrict__ delta, const ushortT* __restrict__ xin,
                const float* __restrict__ dbc, const ushortT* __restrict__ zb,
                const float* __restrict__ a_log, const float* __restrict__ dvec,
                const float* __restrict__ hend, const float* __restrict__ sdl,
                ushortT* __restrict__ y)
{
    __shared__ float BsL[CLEN * 16];
    __shared__ float CsL[CLEN * 16];
    const int tid = threadIdx.x;
    const int bid = blockIdx.x;
    const int eg = bid % EGB;
    const int c  = (bid / EGB) % C_CH;
    const int b  = bid / (EGB * C_CH);
    const int e  = eg * 64 + tid;
    const int l0 = c * CLEN;
    const int rb = b * L_TOK + l0;

    for (int i = tid; i < CLEN * 16; i += 64) {
        int s = i >> 4, n = i & 15;
        size_t row = (size_t)(rb + s) * 80;
        BsL[i] = dbc[row + 48 + n];
        CsL[i] = dbc[row + 64 + n];
    }
    __syncthreads();

    float a[16];
    const float* ar = a_log + (size_t)e * 16;
#pragma unroll
    for (int n = 0; n < 16; ++n) a[n] = -__expf(ar[n]);
    const float dcf = dvec[e];

    float h[16];
#pragma unroll
    for (int n = 0; n < 16; ++n) h[n] = 0.f;
    const float* hb = hend + (((size_t)b * ED + e) * C_CH) * 16;
    const float* sb = sdl + ((size_t)b * ED + e) * C_CH;
    for (int cc = 0; cc < c; ++cc) {
        float sv = sb[cc];
#pragma unroll
        for (int n = 0; n < 16; ++n)
            h[n] = __expf(a[n] * sv) * h[n] + hb[cc * 16 + n];
    }

    const size_t base = (size_t)rb * ED + e;
    float rdl[7], rxi[7], rz[7];
#pragma unroll
    for (int j = 0; j < 7; ++j) {
        rdl[j] = bf2f(delta[base + (size_t)j * ED]);
        rxi[j] = bf2f(xin[base + (size_t)j * ED]);
        rz[j]  = bf2f(zb[base + (size_t)j * ED]);
    }
    for (int s0 = 0; s0 < CLEN; s0 += 7) {
#pragma unroll
        for (int j = 0; j < 7; ++j) {
            const int s = s0 + j;
            float dl = rdl[j], xi = rxi[j], z = rz[j];
            int sp = s + 7; if (sp > CLEN - 1) sp = CLEN - 1;   // clamped prefetch
            rdl[j] = bf2f(delta[base + (size_t)sp * ED]);
            rxi[j] = bf2f(xin[base + (size_t)sp * ED]);
            rz[j]  = bf2f(zb[base + (size_t)sp * ED]);
            float dlxi = dl * xi;
            float yv = 0.f;
#pragma unroll
            for (int n = 0; n < 16; ++n) {
                h[n] = __expf(dl * a[n]) * h[n] + dlxi * BsL[s * 16 + n];
                yv += h[n] * CsL[s * 16 + n];
            }
            yv += dcf * xi;
            float sz = z / (1.f + __expf(-z));
            y[base + (size_t)s * ED] = f2bf(yv * sz);
        }
    }
}

// ----------------------------------------------------------------------------
// im2col for patch embed: P[r, k] (bf16) with r=(b, img, patch), k=(c,ph,pw)
// ----------------------------------------------------------------------------
__global__ __launch_bounds__(256)
void im2col_kernel(const float* __restrict__ rgb, const float* __restrict__ timg,
                   ushortT* __restrict__ P)
{
    int idx = blockIdx.x * 256 + threadIdx.x;
    if (idx >= ROWS * DM) return;
    int k = idx % DM;
    int r = idx / DM;
    int b = r / L_TOK;
    int l = r % L_TOK;
    const float* img = (l < 196) ? rgb : timg;
    int p  = (l < 196) ? l : l - 196;
    int py = p / 14, px = p % 14;
    int c  = k >> 8;
    int ph = (k >> 4) & 15;
    int pw = k & 15;
    P[idx] = f2bf(img[(((size_t)b * 3 + c) * 224 + (py * 16 + ph)) * 224 + (px * 16 + pw)]);
}

// ----------------------------------------------------------------------------
// Output: out[(l*768 + d)*8 + b] = x[b, l, d]
// ----------------------------------------------------------------------------
__global__ __launch_bounds__(256)
void out_transpose_kernel(const float* __restrict__ x, float* __restrict__ out)
{
    int idx = blockIdx.x * 256 + threadIdx.x;
    if (idx >= ROWS * DM) return;
    int b = idx & 7;
    int d = (idx >> 3) % DM;
    int l = idx / (8 * DM);
    out[idx] = x[((size_t)(b * L_TOK + l)) * DM + d];
}

// ----------------------------------------------------------------------------
extern "C" void kernel_launch(void* const* d_in, const int* in_sizes, int n_in,
                              void* d_out, int out_size, void* d_ws, size_t ws_size,
                              hipStream_t stream)
{
    (void)in_sizes; (void)n_in; (void)out_size; (void)ws_size;

    const float* rgb  = (const float*)d_in[0];
    const float* timg = (const float*)d_in[1];
    const float* pe_w = (const float*)d_in[2];   // [768, 3,16,16] -> [768][768]
    const float* pe_b = (const float*)d_in[3];
    const float* in_w = (const float*)d_in[4];   // [8, 3072, 768]
    const float* cw   = (const float*)d_in[5];   // [8, 1536, 1, 4]
    const float* cb   = (const float*)d_in[6];   // [8, 1536]
    const float* xw   = (const float*)d_in[7];   // [8, 80, 1536]
    const float* dtw  = (const float*)d_in[8];   // [8, 1536, 48]
    const float* dtb  = (const float*)d_in[9];   // [8, 1536]
    const float* alog = (const float*)d_in[10];  // [8, 1536, 16]
    const float* dvec = (const float*)d_in[11];  // [8, 1536]
    const float* ow   = (const float*)d_in[12];  // [8, 768, 1536]
    const float* nw   = (const float*)d_in[13];  // [8, 768]

    char* p = (char*)d_ws;
    float*   X   = (float*)p;    p += (size_t)ROWS * DM * 4;
    ushortT* XC  = (ushortT*)p;  p += (size_t)ROWS * ED * 2;   // conv-in / patches / y
    ushortT* Zb  = (ushortT*)p;  p += (size_t)ROWS * ED * 2;
    ushortT* XIN = (ushortT*)p;  p += (size_t)ROWS * ED * 2;
    ushortT* DEL = (ushortT*)p;  p += (size_t)ROWS * ED * 2;   // delta; front = xn
    float*   DBC = (float*)p;    p += (size_t)ROWS * 80 * 4;
    ushortT* XN  = DEL;          // overlay: xn dead before delta is written

    // d_out scratch (dead until out_transpose); POUT and HEND/SDL have
    // disjoint lifetimes within a layer (POUT dies at reduce, HEND born after):
    //   POUT: XP_Z*ROWS*80*4 = 8.03 MB <= out bytes (9.63 MB)
    //   HEND: 6.29 MB + SDL 0.39 MB
    float* POUT = (float*)d_out;
    float* HEND = (float*)d_out;
    float* SDL  = HEND + (size_t)BATCH * ED * C_CH * 16;

    dim3 b256(256);
    const int MT = (ROWS + 127) / 128;            // 25 M-tiles
    const int SCAN_BLOCKS = BATCH * C_CH * EGB;   // 1536

    // ---- patch embed: im2col (bf16) into XC, then MFMA GEMM+bias -> X ----
    im2col_kernel<<<(ROWS * DM + 255) / 256, b256, 0, stream>>>(rgb, timg, XC);
    gemm_mfma<EPI_BIAS, false, false, false, false><<<dim3(DM / 128, MT), b256, 0, stream>>>(
        XC, DM, pe_w, DM, pe_b, X, nullptr, DM, ROWS, DM, DM, DM);

    for (int i = 0; i < 8; ++i) {
        const float* in_wi = in_w + (size_t)i * 2 * ED * DM;
        const float* cwi   = cw   + (size_t)i * ED * 4;
        const float* cbi   = cb   + (size_t)i * ED;
        const float* xwi   = xw   + (size_t)i * 80 * ED;
        const float* dtwi  = dtw  + (size_t)i * ED * DTR;
        const float* dtbi  = dtb  + (size_t)i * ED;
        const float* ali   = alog + (size_t)i * ED * NST;
        const float* dvi   = dvec + (size_t)i * ED;
        const float* owi   = ow   + (size_t)i * DM * ED;
        const float* nwi   = nw   + (size_t)i * DM;

        // xn = rmsnorm(x)  -> XN (bf16, overlaid on DEL)
        rmsnorm_kernel<<<ROWS, b256, 0, stream>>>(X, nwi, XN);
        // [xc | z] = xn @ in_w^T  (single MFMA dispatch, block-uniform split)
        gemm_mfma<EPI_STORE, true, true, false, false><<<dim3(2 * ED / 128, MT), b256, 0, stream>>>(
            XN, DM, in_wi, DM, nullptr, XC, Zb, ED, ROWS, 2 * ED, DM, DM);
        // xin = silu(causal_conv(xc) + cb)
        conv_silu_kernel<<<(ROWS * ED + 255) / 256, b256, 0, stream>>>(
            XC, cwi, cbi, XIN);
        // dbc = xin @ xw^T  (MFMA, N=80 padded to one 128-tile, split-K=8,
        // fp32 partials in d_out, then reduce -> DBC)
        gemm_mfma<EPI_STORE, false, false, false, true><<<dim3(1, MT, XP_Z), b256, 0, stream>>>(
            XIN, ED, xwi, ED, nullptr, POUT, nullptr, 80, ROWS, 80, ED, ED / XP_Z);
        reduce_partials_kernel<<<(ROWS * 80 + 255) / 256, b256, 0, stream>>>(
            POUT, DBC);
        // delta = softplus(dbc[:, :48] @ dtw^T + dtb) -> DEL bf16   (VALU: K=48)
        gemm_nt<EPI_BIAS_SOFTPLUS, false, true><<<dim3(ED / 64, ROWS / 64), b256, 0, stream>>>(
            DBC, 80, dtwi, DTR, dtbi, DEL, ED, ROWS, ED, DTR);
        // chunked scan: pass1 summaries -> pass2 seeded scan + y  -> XC
        scan_part1<<<SCAN_BLOCKS, 64, 0, stream>>>(
            DEL, XIN, DBC, ali, HEND, SDL);
        scan_part2<<<SCAN_BLOCKS, 64, 0, stream>>>(
            DEL, XIN, DBC, Zb, ali, dvi, HEND, SDL, XC);
        // x += y @ ow^T   (MFMA, split-K z=2, atomic fp32 accumulate into X)
        gemm_mfma<EPI_ADD, false, false, true, false><<<dim3(DM / 128, MT, 2), b256, 0, stream>>>(
            XC, ED, owi, ED, nullptr, X, nullptr, DM, ROWS, DM, ED, ED / 2);
    }

    out_transpose_kernel<<<(ROWS * DM + 255) / 256, b256, 0, stream>>>(
        X, (float*)d_out);
}